// Round 1
// baseline (2601.569 us; speedup 1.0000x reference)
//
#include <hip/hip_runtime.h>
#include <math.h>

#define BB 16
#define CC 256
#define HH 64
#define WW 64
#define NN 4096   // HH*WW
#define SS 64
#define NHEAD 8
#define DH 32
#define HID 512
#define DC 64

__device__ __forceinline__ float geluf(float x){
  return 0.5f * x * (1.0f + erff(x * 0.70710678118654752f));
}

__device__ __forceinline__ float waveSum(float v){
#pragma unroll
  for (int m = 32; m >= 1; m >>= 1) v += __shfl_xor(v, m, 64);
  return v;
}
__device__ __forceinline__ float waveMax(float v){
#pragma unroll
  for (int m = 32; m >= 1; m >>= 1) v = fmaxf(v, __shfl_xor(v, m, 64));
  return v;
}
// 256-thread block sum; leading sync makes back-to-back reuse of s4 safe
__device__ __forceinline__ float blockSum256(float v, float* s4){
  v = waveSum(v);
  __syncthreads();
  if ((threadIdx.x & 63) == 0) s4[threadIdx.x >> 6] = v;
  __syncthreads();
  return s4[0] + s4[1] + s4[2] + s4[3];
}

// ---------------- K0: x NCHW -> NHWC ----------------
__global__ __launch_bounds__(256) void k_nchw2nhwc(const float* __restrict__ in, float* __restrict__ out){
  __shared__ float tile[32][33];
  int b = blockIdx.z;
  int n0 = blockIdx.x * 32;
  int c0 = blockIdx.y * 32;
  int tx = threadIdx.x, ty = threadIdx.y;
  const float* src = in + (size_t)b * CC * NN;
  float* dst = out + (size_t)b * NN * CC;
#pragma unroll
  for (int i = 0; i < 32; i += 8)
    tile[ty + i][tx] = src[(size_t)(c0 + ty + i) * NN + n0 + tx];
  __syncthreads();
#pragma unroll
  for (int i = 0; i < 32; i += 8)
    dst[(size_t)(n0 + ty + i) * CC + c0 + tx] = tile[tx][ty + i];
}

// ---------------- K1: 8x8 pooled slots + l2norm ----------------
__global__ __launch_bounds__(256) void k_pool(const float* __restrict__ xnhwc, float* __restrict__ slotsN){
  int bs = blockIdx.x; int b = bs >> 6, s = bs & 63;
  int sy = (s >> 3) * 8, sx = (s & 7) * 8;
  int c = threadIdx.x;
  const float* base = xnhwc + (size_t)b * NN * CC;
  float acc = 0.f;
#pragma unroll
  for (int i = 0; i < 8; i++){
    int rowbase = (sy + i) * WW + sx;
#pragma unroll
    for (int j = 0; j < 8; j++) acc += base[(size_t)(rowbase + j) * CC + c];
  }
  acc *= (1.0f / 64.0f);
  __shared__ float s4[4];
  float ss = blockSum256(acc * acc, s4);
  float inv = 1.0f / fmaxf(sqrtf(ss), 1e-12f);
  slotsN[(size_t)bs * CC + c] = acc * inv;
}

// ---------------- K2/K8: LayerNorm over channels (+ optional row l2 inv-norm) ----------------
__global__ __launch_bounds__(256) void k_ln(const float* __restrict__ xin, const float* __restrict__ w,
                                            const float* __restrict__ b, float* __restrict__ xout,
                                            float* __restrict__ rn){
  int id = blockIdx.x;           // b*NN + n
  int t = threadIdx.x;           // c
  const float* row = xin + (size_t)id * CC;
  float v = row[t];
  __shared__ float s4[4];
  float mu = blockSum256(v, s4) * (1.0f / CC);
  float d = v - mu;
  float var = blockSum256(d * d, s4) * (1.0f / CC);
  float xv = d * rsqrtf(var + 1e-5f) * w[t] + b[t];
  xout[(size_t)id * CC + t] = xv;
  if (rn){
    float ss = blockSum256(xv * xv, s4);
    if (t == 0) rn[id] = 1.0f / fmaxf(sqrtf(ss), 1e-12f);
  }
}

// ---------------- K4: logits[b,s,n] = scale * rn[n] * dot(slotsN[s], xn[n]) ----------------
__global__ __launch_bounds__(256) void k_logits(const float* __restrict__ slotsN, const float* __restrict__ xn,
                                                const float* __restrict__ rn, const float* __restrict__ scale_p,
                                                float* __restrict__ logits){
  __shared__ float ls[32 * 257];
  __shared__ float lx[8 * 257];
  int b = blockIdx.z;
  int n0 = blockIdx.x * 8;
  int s0 = blockIdx.y * 32;
  int t = threadIdx.x;
  for (int idx = t; idx < 32 * 256; idx += 256){
    int r = idx >> 8, k = idx & 255;
    ls[r * 257 + k] = slotsN[(size_t)(b * SS + s0 + r) * CC + k];
  }
  for (int idx = t; idx < 8 * 256; idx += 256){
    int r = idx >> 8, k = idx & 255;
    lx[r * 257 + k] = xn[((size_t)b * NN + n0 + r) * CC + k];
  }
  __syncthreads();
  int s = t & 31, q = t >> 5;
  float a = 0.f;
  for (int k = 0; k < 256; k++) a += ls[s * 257 + k] * lx[q * 257 + k];
  int n = n0 + q;
  logits[((size_t)b * SS + s0 + s) * NN + n] = a * scale_p[0] * rn[b * NN + n];
}

// ---------------- K5: slots[b,s,c] = softmax_n(logits[b,s,:]) @ xn ----------------
__global__ __launch_bounds__(256) void k_slots_agg(const float* __restrict__ logits, const float* __restrict__ xn,
                                                   float* __restrict__ slotsA){
  int b = blockIdx.x >> 6, s = blockIdx.x & 63;
  const float* L = logits + ((size_t)b * SS + s) * NN;
  int t = threadIdx.x;
  __shared__ float s4[4];
  __shared__ float wbuf[256];
  float m = -1e30f;
  for (int n = t; n < NN; n += 256) m = fmaxf(m, L[n]);
  m = waveMax(m);
  __syncthreads();
  if ((t & 63) == 0) s4[t >> 6] = m;
  __syncthreads();
  m = fmaxf(fmaxf(s4[0], s4[1]), fmaxf(s4[2], s4[3]));
  float z = 0.f;
  for (int n = t; n < NN; n += 256) z += expf(L[n] - m);
  z = blockSum256(z, s4);
  float inv = 1.0f / z;
  const float* X = xn + (size_t)b * NN * CC;
  float acc = 0.f;
  for (int n0 = 0; n0 < NN; n0 += 256){
    __syncthreads();
    wbuf[t] = expf(L[n0 + t] - m);
    __syncthreads();
    for (int i = 0; i < 256; i++)
      acc += wbuf[i] * X[(size_t)(n0 + i) * CC + t];
  }
  slotsA[((size_t)b * SS + s) * CC + t] = acc * inv;
}

// ---------------- K6a: qkv = slots @ Wi^T + bi ----------------
__global__ __launch_bounds__(256) void k_qkv(const float* __restrict__ sla, const float* __restrict__ wi,
                                             const float* __restrict__ bi, float* __restrict__ qkv){
  int bs = blockIdx.x;
  int t = threadIdx.x;
  __shared__ float srow[256];
  srow[t] = sla[(size_t)bs * CC + t];
  __syncthreads();
  for (int r = 0; r < 3; r++){
    int j = r * 256 + t;
    const float* wrow = wi + (size_t)j * CC;
    float a = bi[j];
    for (int k = 0; k < CC; k++) a += srow[k] * wrow[k];
    qkv[(size_t)bs * 768 + j] = a;
  }
}

// ---------------- K6b: per (b,h) attention over S=64 ----------------
__global__ __launch_bounds__(256) void k_attn(const float* __restrict__ qkv, float* __restrict__ ao){
  int b = blockIdx.x >> 3, h = blockIdx.x & 7;
  __shared__ float lq[64][33], lk[64][33], lv[64][33];
  __shared__ float sc[64][65];
  int t = threadIdx.x;
  for (int idx = t; idx < 64 * 32; idx += 256){
    int s = idx >> 5, d = idx & 31;
    const float* base = qkv + ((size_t)b * SS + s) * 768 + h * DH + d;
    lq[s][d] = base[0];
    lk[s][d] = base[256];
    lv[s][d] = base[512];
  }
  __syncthreads();
  const float rs = 0.17677669529663687f; // 1/sqrt(32)
  for (int idx = t; idx < 64 * 64; idx += 256){
    int qq = idx >> 6, kk = idx & 63;
    float a = 0.f;
#pragma unroll
    for (int d = 0; d < 32; d++) a += lq[qq][d] * lk[kk][d];
    sc[qq][kk] = a * rs;
  }
  __syncthreads();
  if (t < 64){
    float m = -1e30f;
    for (int k = 0; k < 64; k++) m = fmaxf(m, sc[t][k]);
    float z = 0.f;
    for (int k = 0; k < 64; k++){ float e = expf(sc[t][k] - m); sc[t][k] = e; z += e; }
    float iv = 1.0f / z;
    for (int k = 0; k < 64; k++) sc[t][k] *= iv;
  }
  __syncthreads();
  for (int idx = t; idx < 64 * 32; idx += 256){
    int qq = idx >> 5, d = idx & 31;
    float a = 0.f;
#pragma unroll
    for (int k = 0; k < 64; k++) a += sc[qq][k] * lv[k][d];
    ao[((size_t)b * SS + qq) * CC + h * DH + d] = a;
  }
}

// ---------------- K6c: out projection ----------------
__global__ __launch_bounds__(256) void k_oproj(const float* __restrict__ ao, const float* __restrict__ wo,
                                               const float* __restrict__ bo, float* __restrict__ sl2){
  int bs = blockIdx.x;
  int t = threadIdx.x;
  __shared__ float srow[256];
  srow[t] = ao[(size_t)bs * CC + t];
  __syncthreads();
  const float* wrow = wo + (size_t)t * CC;
  float a = bo[t];
  for (int k = 0; k < CC; k++) a += srow[k] * wrow[k];
  sl2[(size_t)bs * CC + t] = a;
}

// ---------------- K7a: P[b,n,s] = softmax_s(logits[b,:,n]) ----------------
__global__ __launch_bounds__(256) void k_probsT(const float* __restrict__ logits, float* __restrict__ P){
  int b = blockIdx.y;
  int n = blockIdx.x * 4 + (threadIdx.x >> 6);
  int s = threadIdx.x & 63;
  float l = logits[((size_t)b * SS + s) * NN + n];
  float m = waveMax(l);
  float e = expf(l - m);
  float z = waveSum(e);
  P[((size_t)b * NN + n) * SS + s] = e / z;
}

// ---------------- K7b: W0 += P @ slots2  (residual add of mixed output) ----------------
__global__ __launch_bounds__(256) void k_out_res(const float* __restrict__ P, const float* __restrict__ sl2,
                                                 float* __restrict__ W0buf){
  int b = blockIdx.y;
  int n0 = blockIdx.x * 16;
  int t = threadIdx.x;  // c
  __shared__ float ls[32 * 257];
  __shared__ float lp[16 * 64];
  for (int idx = t; idx < 16 * 64; idx += 256)
    lp[idx] = P[((size_t)b * NN + n0 + (idx >> 6)) * SS + (idx & 63)];
  float acc[16];
#pragma unroll
  for (int i = 0; i < 16; i++)
    acc[i] = W0buf[((size_t)b * NN + n0 + i) * CC + t];
  for (int half = 0; half < 2; half++){
    __syncthreads();
    for (int idx = t; idx < 32 * 256; idx += 256){
      int r = idx >> 8, k = idx & 255;
      ls[r * 257 + k] = sl2[((size_t)b * SS + half * 32 + r) * CC + k];
    }
    __syncthreads();
#pragma unroll
    for (int i = 0; i < 16; i++){
      float a = acc[i];
      for (int s2 = 0; s2 < 32; s2++)
        a += lp[i * 64 + half * 32 + s2] * ls[s2 * 257 + t];
      acc[i] = a;
    }
  }
#pragma unroll
  for (int i = 0; i < 16; i++)
    W0buf[((size_t)b * NN + n0 + i) * CC + t] = acc[i];
}

// ---------------- K9a0: transpose pconv weights to [ci*9+kidx][co] ----------------
__global__ __launch_bounds__(256) void k_wt(const float* __restrict__ w, float* __restrict__ wT){
  int i = blockIdx.x * 256 + threadIdx.x;
  if (i >= 64 * 64 * 9) return;
  int co = i / 576, rem = i % 576;
  wT[(size_t)rem * 64 + co] = w[i];
}

// ---------------- K9a: partial conv 3x3 on channels 0..63 (NHWC) ----------------
__global__ __launch_bounds__(256) void k_pconv(const float* __restrict__ xn2, const float* __restrict__ wT,
                                               float* __restrict__ xt){
  int b = blockIdx.y;
  int n = blockIdx.x * 4 + (threadIdx.x >> 6);
  int co = threadIdx.x & 63;
  int y = n >> 6, x = n & 63;
  float acc = 0.f;
  for (int ky = 0; ky < 3; ky++){
    int iy = y + ky - 1; if (iy < 0 || iy >= HH) continue;
    for (int kx = 0; kx < 3; kx++){
      int ix = x + kx - 1; if (ix < 0 || ix >= WW) continue;
      const float* irow = xn2 + ((size_t)b * NN + iy * WW + ix) * CC;
      const float* wp = wT + (size_t)(ky * 3 + kx) * 64 + co;
#pragma unroll 8
      for (int ci = 0; ci < 64; ci++)
        acc += irow[ci] * wp[(size_t)ci * 576];
    }
  }
  xt[((size_t)b * NN + n) * CC + co] = acc;
}

// ---------------- K9b: copy channels 64..255 into xt ----------------
__global__ __launch_bounds__(256) void k_copy192(const float* __restrict__ xn2, float* __restrict__ xt){
  size_t i = (size_t)blockIdx.x * 256 + threadIdx.x;  // over BB*NN*192, exact multiple
  size_t n = i / 192;
  int c = (int)(i % 192) + 64;
  xt[n * CC + c] = xn2[n * CC + c];
}

// ---------------- K10: lin1 GEMM + GELU, route into Y1/Y2 ----------------
__global__ __launch_bounds__(256) void k_lin1(const float* __restrict__ xt, const float* __restrict__ w1,
                                              const float* __restrict__ b1, float* __restrict__ Y1,
                                              float* __restrict__ Y2, int rowbase){
  __shared__ float lA[64 * 65];
  __shared__ float lB[64 * 65];
  int t = threadIdx.x;
  int m0 = blockIdx.x * 64;          // chunk-local row
  int n0 = blockIdx.y * 64;          // output feature j
  size_t R0 = (size_t)rowbase + m0;  // global row into xt
  float acc[16];
#pragma unroll
  for (int i = 0; i < 16; i++) acc[i] = 0.f;
  for (int kb = 0; kb < 256; kb += 64){
    __syncthreads();
    for (int idx = t; idx < 64 * 64; idx += 256){
      int r = idx >> 6, k = idx & 63;
      lA[r * 65 + k] = xt[(R0 + r) * (size_t)CC + kb + k];
      lB[r * 65 + k] = w1[(size_t)(n0 + r) * CC + kb + k];
    }
    __syncthreads();
    int tr = t >> 4, tc = t & 15;
    for (int k = 0; k < 64; k++){
      float a0 = lA[(tr * 4 + 0) * 65 + k], a1 = lA[(tr * 4 + 1) * 65 + k];
      float a2 = lA[(tr * 4 + 2) * 65 + k], a3 = lA[(tr * 4 + 3) * 65 + k];
      float w0 = lB[(tc * 4 + 0) * 65 + k], w1_ = lB[(tc * 4 + 1) * 65 + k];
      float w2 = lB[(tc * 4 + 2) * 65 + k], w3 = lB[(tc * 4 + 3) * 65 + k];
      acc[0]  += a0 * w0; acc[1]  += a0 * w1_; acc[2]  += a0 * w2; acc[3]  += a0 * w3;
      acc[4]  += a1 * w0; acc[5]  += a1 * w1_; acc[6]  += a1 * w2; acc[7]  += a1 * w3;
      acc[8]  += a2 * w0; acc[9]  += a2 * w1_; acc[10] += a2 * w2; acc[11] += a2 * w3;
      acc[12] += a3 * w0; acc[13] += a3 * w1_; acc[14] += a3 * w2; acc[15] += a3 * w3;
    }
  }
  int tr = t >> 4, tc = t & 15;
#pragma unroll
  for (int i = 0; i < 4; i++){
    int rl = m0 + tr * 4 + i;   // chunk-local row
#pragma unroll
    for (int u = 0; u < 4; u++){
      int j = n0 + tc * 4 + u;
      float v = geluf(acc[i * 4 + u] + b1[j]);
      if (j < HID) Y1[(size_t)rl * HID + j] = v;
      else         Y2[(size_t)rl * HID + (j - HID)] = v;
    }
  }
}

// ---------------- K11: depthwise conv 3x3 + GELU (NHWC) ----------------
__global__ __launch_bounds__(256) void k_dwconv(const float* __restrict__ Y1, const float* __restrict__ dww,
                                                const float* __restrict__ dwb, float* __restrict__ Y1D){
  __shared__ float lw[HID * 9];
  __shared__ float lb[HID];
  int t = threadIdx.x;
  for (int idx = t; idx < HID * 9; idx += 256) lw[idx] = dww[idx];
  for (int idx = t; idx < HID; idx += 256) lb[idx] = dwb[idx];
  __syncthreads();
  int n = blockIdx.x; int bl = blockIdx.y;
  int y = n >> 6, x = n & 63;
  const float* base = Y1 + (size_t)bl * NN * HID;
#pragma unroll
  for (int half = 0; half < 2; half++){
    int ch = half * 256 + t;
    float acc = lb[ch];
    for (int ky = 0; ky < 3; ky++){
      int iy = y + ky - 1; if (iy < 0 || iy >= HH) continue;
      for (int kx = 0; kx < 3; kx++){
        int ix = x + kx - 1; if (ix < 0 || ix >= WW) continue;
        acc += base[(size_t)(iy * WW + ix) * HID + ch] * lw[ch * 9 + ky * 3 + kx];
      }
    }
    Y1D[((size_t)bl * NN + n) * HID + ch] = geluf(acc);
  }
}

// ---------------- K12: lin2 GEMM on (y1d*y2), += into W0 ----------------
__global__ __launch_bounds__(256) void k_lin2(const float* __restrict__ Y1D, const float* __restrict__ Y2,
                                              const float* __restrict__ w2, const float* __restrict__ b2,
                                              float* __restrict__ W0buf, int rowbase){
  __shared__ float lA[64 * 65];
  __shared__ float lB[64 * 65];
  int t = threadIdx.x;
  int m0 = blockIdx.x * 64;
  int n0 = blockIdx.y * 64;  // c tile
  float acc[16];
#pragma unroll
  for (int i = 0; i < 16; i++) acc[i] = 0.f;
  for (int kb = 0; kb < HID; kb += 64){
    __syncthreads();
    for (int idx = t; idx < 64 * 64; idx += 256){
      int r = idx >> 6, k = idx & 63;
      size_t rl = (size_t)(m0 + r);
      lA[r * 65 + k] = Y1D[rl * HID + kb + k] * Y2[rl * HID + kb + k];
      lB[r * 65 + k] = w2[(size_t)(n0 + r) * HID + kb + k];
    }
    __syncthreads();
    int tr = t >> 4, tc = t & 15;
    for (int k = 0; k < 64; k++){
      float a0 = lA[(tr * 4 + 0) * 65 + k], a1 = lA[(tr * 4 + 1) * 65 + k];
      float a2 = lA[(tr * 4 + 2) * 65 + k], a3 = lA[(tr * 4 + 3) * 65 + k];
      float w0 = lB[(tc * 4 + 0) * 65 + k], w1_ = lB[(tc * 4 + 1) * 65 + k];
      float w2_ = lB[(tc * 4 + 2) * 65 + k], w3 = lB[(tc * 4 + 3) * 65 + k];
      acc[0]  += a0 * w0; acc[1]  += a0 * w1_; acc[2]  += a0 * w2_; acc[3]  += a0 * w3;
      acc[4]  += a1 * w0; acc[5]  += a1 * w1_; acc[6]  += a1 * w2_; acc[7]  += a1 * w3;
      acc[8]  += a2 * w0; acc[9]  += a2 * w1_; acc[10] += a2 * w2_; acc[11] += a2 * w3;
      acc[12] += a3 * w0; acc[13] += a3 * w1_; acc[14] += a3 * w2_; acc[15] += a3 * w3;
    }
  }
  int tr = t >> 4, tc = t & 15;
#pragma unroll
  for (int i = 0; i < 4; i++){
    size_t gr = (size_t)rowbase + m0 + tr * 4 + i;  // global row
#pragma unroll
    for (int u = 0; u < 4; u++){
      int c = n0 + tc * 4 + u;
      W0buf[gr * CC + c] += acc[i * 4 + u] + b2[c];
    }
  }
}

// ---------------- K13: final NHWC->NCHW, write both outputs ----------------
__global__ __launch_bounds__(256) void k_final(const float* __restrict__ W0buf, const float* __restrict__ xin,
                                               float* __restrict__ out){
  __shared__ float tile[32][33];
  int b = blockIdx.z;
  int n0 = blockIdx.x * 32, c0 = blockIdx.y * 32;
  int tx = threadIdx.x, ty = threadIdx.y;
  const float* src = W0buf + (size_t)b * NN * CC;
#pragma unroll
  for (int i = 0; i < 32; i += 8)
    tile[ty + i][tx] = src[(size_t)(n0 + ty + i) * CC + c0 + tx];
  __syncthreads();
  float* o1 = out + (size_t)BB * CC * NN;
#pragma unroll
  for (int i = 0; i < 32; i += 8){
    size_t gi = (size_t)b * CC * NN + (size_t)(c0 + ty + i) * NN + n0 + tx;
    float v = tile[tx][ty + i];
    out[gi] = v;
    o1[gi] = xin[gi] - v;
  }
}

extern "C" void kernel_launch(void* const* d_in, const int* in_sizes, int n_in,
                              void* d_out, int out_size, void* d_ws, size_t ws_size,
                              hipStream_t stream){
  const float* x       = (const float*)d_in[0];
  const float* scale_p = (const float*)d_in[1];
  const float* n1w     = (const float*)d_in[2];
  const float* n1b     = (const float*)d_in[3];
  const float* wi      = (const float*)d_in[4];
  const float* bi      = (const float*)d_in[5];
  const float* wo      = (const float*)d_in[6];
  const float* bo      = (const float*)d_in[7];
  const float* n2w     = (const float*)d_in[8];
  const float* n2b     = (const float*)d_in[9];
  const float* pw      = (const float*)d_in[10];
  const float* w1      = (const float*)d_in[11];
  const float* b1      = (const float*)d_in[12];
  const float* dww     = (const float*)d_in[13];
  const float* dwb     = (const float*)d_in[14];
  const float* w2      = (const float*)d_in[15];
  const float* b2      = (const float*)d_in[16];

  // ---- workspace layout (floats) ----
  float* base = (float*)d_ws;
  size_t off = 0;
  float* W0  = base + off; off += (size_t)BB * NN * CC;     // x NHWC -> x_after -> x_final (16.78M)
  float* SLN = base + off; off += (size_t)BB * SS * CC;     // l2norm'd init slots
  float* SLA = base + off; off += (size_t)BB * SS * CC;     // aggregated slots
  float* QKV = base + off; off += (size_t)BB * SS * 3 * CC;
  float* AO  = base + off; off += (size_t)BB * SS * CC;
  float* SL2 = base + off; off += (size_t)BB * SS * CC;     // slots after MHA
  float* RN  = base + off; off += (size_t)BB * NN;          // 1/||xn row||
  float* WT  = base + off; off += (size_t)64 * 64 * 9;      // transposed pconv weights
  float* P   = base + off; off += (size_t)BB * NN * SS;     // softmax_s probs
  float* Y2c = base + off; off += (size_t)4 * NN * HID;     // chunk y2
  if (ws_size < off * sizeof(float)) return;  // insufficient scratch — bail loudly

  // d_out halves double as scratch until k_final rewrites everything:
  float* XN = (float*)d_out;                          // xn -> xn2 -> {Y1, Y1D} chunks
  float* LG = (float*)d_out + (size_t)BB * NN * CC;   // logits -> xt
  float* OUT = (float*)d_out;

  dim3 tb2(32, 8);
  k_nchw2nhwc<<<dim3(NN / 32, CC / 32, BB), tb2, 0, stream>>>(x, W0);
  k_pool<<<BB * SS, 256, 0, stream>>>(W0, SLN);
  k_ln<<<BB * NN, 256, 0, stream>>>(W0, n1w, n1b, XN, RN);
  k_logits<<<dim3(NN / 8, SS / 32, BB), 256, 0, stream>>>(SLN, XN, RN, scale_p, LG);
  k_slots_agg<<<BB * SS, 256, 0, stream>>>(LG, XN, SLA);
  k_qkv<<<BB * SS, 256, 0, stream>>>(SLA, wi, bi, QKV);
  k_attn<<<BB * NHEAD, 256, 0, stream>>>(QKV, AO);
  k_oproj<<<BB * SS, 256, 0, stream>>>(AO, wo, bo, SL2);
  k_probsT<<<dim3(NN / 4, BB), 256, 0, stream>>>(LG, P);
  k_out_res<<<dim3(NN / 16, BB), 256, 0, stream>>>(P, SL2, W0);
  // FRFN
  k_ln<<<BB * NN, 256, 0, stream>>>(W0, n2w, n2b, XN, (float*)nullptr);
  k_wt<<<(64 * 64 * 9 + 255) / 256, 256, 0, stream>>>(pw, WT);
  k_pconv<<<dim3(NN / 4, BB), 256, 0, stream>>>(XN, WT, LG);
  k_copy192<<<(BB * NN * 192) / 256, 256, 0, stream>>>(XN, LG);
  for (int ch = 0; ch < 4; ch++){
    int rowbase = ch * 4 * NN;                 // global row offset into xt / W0
    float* Y1  = XN;                           // 4*NN*HID floats
    float* Y1D = XN + (size_t)4 * NN * HID;    // fills the rest of d_out half0 exactly
    k_lin1<<<dim3(4 * NN / 64, 1024 / 64), 256, 0, stream>>>(LG, w1, b1, Y1, Y2c, rowbase);
    k_dwconv<<<dim3(NN, 4), 256, 0, stream>>>(Y1, dww, dwb, Y1D);
    k_lin2<<<dim3(4 * NN / 64, CC / 64), 256, 0, stream>>>(Y1D, Y2c, w2, b2, W0, rowbase);
  }
  k_final<<<dim3(NN / 32, CC / 32, BB), tb2, 0, stream>>>(W0, x, OUT);
}

// Round 2
// 1223.341 us; speedup vs baseline: 2.1266x; 2.1266x over previous
//
#include <hip/hip_runtime.h>
#include <hip/hip_bf16.h>
#include <stdint.h>
#include <math.h>

#define BB 16
#define CC 256
#define HH 64
#define WW 64
#define NN 4096   // HH*WW
#define SS 64
#define NHEAD 8
#define DH 32
#define HID 512
#define DC 64

typedef float    f32x4  __attribute__((ext_vector_type(4)));
typedef uint16_t u16x8  __attribute__((ext_vector_type(8)));
typedef uint16_t u16x4  __attribute__((ext_vector_type(4)));

__device__ __forceinline__ float geluf(float x){
  return 0.5f * x * (1.0f + erff(x * 0.70710678118654752f));
}
__device__ __forceinline__ uint16_t f2b(float f){
  union { float f; uint32_t u; } v; v.f = f;
  uint32_t r = v.u + 0x7fffu + ((v.u >> 16) & 1u);
  return (uint16_t)(r >> 16);
}
__device__ __forceinline__ float b2f(uint16_t h){
  union { uint32_t u; float f; } v; v.u = ((uint32_t)h) << 16;
  return v.f;
}

__device__ __forceinline__ float waveSum(float v){
#pragma unroll
  for (int m = 32; m >= 1; m >>= 1) v += __shfl_xor(v, m, 64);
  return v;
}
__device__ __forceinline__ float waveMax(float v){
#pragma unroll
  for (int m = 32; m >= 1; m >>= 1) v = fmaxf(v, __shfl_xor(v, m, 64));
  return v;
}
__device__ __forceinline__ float blockSum256(float v, float* s4){
  v = waveSum(v);
  __syncthreads();
  if ((threadIdx.x & 63) == 0) s4[threadIdx.x >> 6] = v;
  __syncthreads();
  return s4[0] + s4[1] + s4[2] + s4[3];
}

// ---- MFMA 16x16x32 bf16 via inline asm (D=C in-place) ----
// A/B frag: lane l holds row/col (l&15), k = (l>>4)*8 + e (8 consecutive bf16)
// D: col = lane&15, row = (lane>>4)*4 + reg   [m89-verified]
__device__ __forceinline__ void mfma_bf16(f32x4& d, u16x8 a, u16x8 b){
  asm volatile("v_mfma_f32_16x16x32_bf16 %0, %1, %2, %0" : "+v"(d) : "v"(a), "v"(b));
}

// shared 4-wave 4x4-fragment core over one BK=64 LDS tile (A rows x 64k, B rows x 64k)
__device__ __forceinline__ void mma_core(const uint16_t* lA, const uint16_t* lB,
                                         f32x4 (&acc)[4][4], int wrow, int wcol, int lane){
  const int rb = lane & 15, kb = (lane >> 4) * 8;
#pragma unroll
  for (int ks = 0; ks < 2; ks++){
    u16x8 af[4], bf[4];
#pragma unroll
    for (int m = 0; m < 4; m++)
      af[m] = *(const u16x8*)&lA[(wrow + m * 16 + rb) * 64 + ks * 32 + kb];
#pragma unroll
    for (int n = 0; n < 4; n++)
      bf[n] = *(const u16x8*)&lB[(wcol + n * 16 + rb) * 64 + ks * 32 + kb];
#pragma unroll
    for (int m = 0; m < 4; m++)
#pragma unroll
      for (int n = 0; n < 4; n++)
        mfma_bf16(acc[m][n], af[m], bf[n]);
  }
}

// ---------------- K0: x NCHW -> NHWC ----------------
__global__ __launch_bounds__(256) void k_nchw2nhwc(const float* __restrict__ in, float* __restrict__ out){
  __shared__ float tile[32][33];
  int b = blockIdx.z;
  int n0 = blockIdx.x * 32;
  int c0 = blockIdx.y * 32;
  int tx = threadIdx.x, ty = threadIdx.y;
  const float* src = in + (size_t)b * CC * NN;
  float* dst = out + (size_t)b * NN * CC;
#pragma unroll
  for (int i = 0; i < 32; i += 8)
    tile[ty + i][tx] = src[(size_t)(c0 + ty + i) * NN + n0 + tx];
  __syncthreads();
#pragma unroll
  for (int i = 0; i < 32; i += 8)
    dst[(size_t)(n0 + ty + i) * CC + c0 + tx] = tile[tx][ty + i];
}

// ---------------- K1: 8x8 pooled slots + l2norm ----------------
__global__ __launch_bounds__(256) void k_pool(const float* __restrict__ xnhwc, float* __restrict__ slotsN){
  int bs = blockIdx.x; int b = bs >> 6, s = bs & 63;
  int sy = (s >> 3) * 8, sx = (s & 7) * 8;
  int c = threadIdx.x;
  const float* base = xnhwc + (size_t)b * NN * CC;
  float acc = 0.f;
#pragma unroll
  for (int i = 0; i < 8; i++){
    int rowbase = (sy + i) * WW + sx;
#pragma unroll
    for (int j = 0; j < 8; j++) acc += base[(size_t)(rowbase + j) * CC + c];
  }
  acc *= (1.0f / 64.0f);
  __shared__ float s4[4];
  float ss = blockSum256(acc * acc, s4);
  float inv = 1.0f / fmaxf(sqrtf(ss), 1e-12f);
  slotsN[(size_t)bs * CC + c] = acc * inv;
}

// ---------------- K2/K8: LayerNorm over channels (+ optional row l2 inv-norm) ----------------
__global__ __launch_bounds__(256) void k_ln(const float* __restrict__ xin, const float* __restrict__ w,
                                            const float* __restrict__ b, float* __restrict__ xout,
                                            float* __restrict__ rn){
  int id = blockIdx.x;           // b*NN + n
  int t = threadIdx.x;           // c
  const float* row = xin + (size_t)id * CC;
  float v = row[t];
  __shared__ float s4[4];
  float mu = blockSum256(v, s4) * (1.0f / CC);
  float d = v - mu;
  float var = blockSum256(d * d, s4) * (1.0f / CC);
  float xv = d * rsqrtf(var + 1e-5f) * w[t] + b[t];
  xout[(size_t)id * CC + t] = xv;
  if (rn){
    float ss = blockSum256(xv * xv, s4);
    if (t == 0) rn[id] = 1.0f / fmaxf(sqrtf(ss), 1e-12f);
  }
}

// ---------------- K4: logits[b,s,n] = scale * rn[n] * dot(slotsN[s], xn[n]) ----------------
__global__ __launch_bounds__(256) void k_logits(const float* __restrict__ slotsN, const float* __restrict__ xn,
                                                const float* __restrict__ rn, const float* __restrict__ scale_p,
                                                float* __restrict__ logits){
  __shared__ float ls[32 * 257];
  __shared__ float lx[8 * 257];
  int b = blockIdx.z;
  int n0 = blockIdx.x * 8;
  int s0 = blockIdx.y * 32;
  int t = threadIdx.x;
  for (int idx = t; idx < 32 * 256; idx += 256){
    int r = idx >> 8, k = idx & 255;
    ls[r * 257 + k] = slotsN[(size_t)(b * SS + s0 + r) * CC + k];
  }
  for (int idx = t; idx < 8 * 256; idx += 256){
    int r = idx >> 8, k = idx & 255;
    lx[r * 257 + k] = xn[((size_t)b * NN + n0 + r) * CC + k];
  }
  __syncthreads();
  int s = t & 31, q = t >> 5;
  float a = 0.f;
  for (int k = 0; k < 256; k++) a += ls[s * 257 + k] * lx[q * 257 + k];
  int n = n0 + q;
  logits[((size_t)b * SS + s0 + s) * NN + n] = a * scale_p[0] * rn[b * NN + n];
}

// ---------------- K5: slots[b,s,c] = softmax_n(logits[b,s,:]) @ xn ----------------
__global__ __launch_bounds__(256) void k_slots_agg(const float* __restrict__ logits, const float* __restrict__ xn,
                                                   float* __restrict__ slotsA){
  int b = blockIdx.x >> 6, s = blockIdx.x & 63;
  const float* L = logits + ((size_t)b * SS + s) * NN;
  int t = threadIdx.x;
  __shared__ float s4[4];
  __shared__ float wbuf[256];
  float m = -1e30f;
  for (int n = t; n < NN; n += 256) m = fmaxf(m, L[n]);
  m = waveMax(m);
  __syncthreads();
  if ((t & 63) == 0) s4[t >> 6] = m;
  __syncthreads();
  m = fmaxf(fmaxf(s4[0], s4[1]), fmaxf(s4[2], s4[3]));
  float z = 0.f;
  for (int n = t; n < NN; n += 256) z += expf(L[n] - m);
  z = blockSum256(z, s4);
  float inv = 1.0f / z;
  const float* X = xn + (size_t)b * NN * CC;
  float acc = 0.f;
  for (int n0 = 0; n0 < NN; n0 += 256){
    __syncthreads();
    wbuf[t] = expf(L[n0 + t] - m);
    __syncthreads();
    for (int i = 0; i < 256; i++)
      acc += wbuf[i] * X[(size_t)(n0 + i) * CC + t];
  }
  slotsA[((size_t)b * SS + s) * CC + t] = acc * inv;
}

// ---------------- K6a: qkv = slots @ Wi^T + bi ----------------
__global__ __launch_bounds__(256) void k_qkv(const float* __restrict__ sla, const float* __restrict__ wi,
                                             const float* __restrict__ bi, float* __restrict__ qkv){
  int bs = blockIdx.x;
  int t = threadIdx.x;
  __shared__ float srow[256];
  srow[t] = sla[(size_t)bs * CC + t];
  __syncthreads();
  for (int r = 0; r < 3; r++){
    int j = r * 256 + t;
    const float* wrow = wi + (size_t)j * CC;
    float a = bi[j];
    for (int k = 0; k < CC; k++) a += srow[k] * wrow[k];
    qkv[(size_t)bs * 768 + j] = a;
  }
}

// ---------------- K6b: per (b,h) attention over S=64 ----------------
__global__ __launch_bounds__(256) void k_attn(const float* __restrict__ qkv, float* __restrict__ ao){
  int b = blockIdx.x >> 3, h = blockIdx.x & 7;
  __shared__ float lq[64][33], lk[64][33], lv[64][33];
  __shared__ float sc[64][65];
  int t = threadIdx.x;
  for (int idx = t; idx < 64 * 32; idx += 256){
    int s = idx >> 5, d = idx & 31;
    const float* base = qkv + ((size_t)b * SS + s) * 768 + h * DH + d;
    lq[s][d] = base[0];
    lk[s][d] = base[256];
    lv[s][d] = base[512];
  }
  __syncthreads();
  const float rs = 0.17677669529663687f; // 1/sqrt(32)
  for (int idx = t; idx < 64 * 64; idx += 256){
    int qq = idx >> 6, kk = idx & 63;
    float a = 0.f;
#pragma unroll
    for (int d = 0; d < 32; d++) a += lq[qq][d] * lk[kk][d];
    sc[qq][kk] = a * rs;
  }
  __syncthreads();
  if (t < 64){
    float m = -1e30f;
    for (int k = 0; k < 64; k++) m = fmaxf(m, sc[t][k]);
    float z = 0.f;
    for (int k = 0; k < 64; k++){ float e = expf(sc[t][k] - m); sc[t][k] = e; z += e; }
    float iv = 1.0f / z;
    for (int k = 0; k < 64; k++) sc[t][k] *= iv;
  }
  __syncthreads();
  for (int idx = t; idx < 64 * 32; idx += 256){
    int qq = idx >> 5, d = idx & 31;
    float a = 0.f;
#pragma unroll
    for (int k = 0; k < 64; k++) a += sc[qq][k] * lv[k][d];
    ao[((size_t)b * SS + qq) * CC + h * DH + d] = a;
  }
}

// ---------------- K6c: out projection ----------------
__global__ __launch_bounds__(256) void k_oproj(const float* __restrict__ ao, const float* __restrict__ wo,
                                               const float* __restrict__ bo, float* __restrict__ sl2){
  int bs = blockIdx.x;
  int t = threadIdx.x;
  __shared__ float srow[256];
  srow[t] = ao[(size_t)bs * CC + t];
  __syncthreads();
  const float* wrow = wo + (size_t)t * CC;
  float a = bo[t];
  for (int k = 0; k < CC; k++) a += srow[k] * wrow[k];
  sl2[(size_t)bs * CC + t] = a;
}

// ---------------- K7a: P[b,n,s] = softmax_s(logits[b,:,n]) ----------------
__global__ __launch_bounds__(256) void k_probsT(const float* __restrict__ logits, float* __restrict__ P){
  int b = blockIdx.y;
  int n = blockIdx.x * 4 + (threadIdx.x >> 6);
  int s = threadIdx.x & 63;
  float l = logits[((size_t)b * SS + s) * NN + n];
  float m = waveMax(l);
  float e = expf(l - m);
  float z = waveSum(e);
  P[((size_t)b * NN + n) * SS + s] = e / z;
}

// ---------------- K7b: W0 += P @ slots2  (residual add of mixed output) ----------------
__global__ __launch_bounds__(256) void k_out_res(const float* __restrict__ P, const float* __restrict__ sl2,
                                                 float* __restrict__ W0buf){
  int b = blockIdx.y;
  int n0 = blockIdx.x * 16;
  int t = threadIdx.x;  // c
  __shared__ float ls[32 * 257];
  __shared__ float lp[16 * 64];
  for (int idx = t; idx < 16 * 64; idx += 256)
    lp[idx] = P[((size_t)b * NN + n0 + (idx >> 6)) * SS + (idx & 63)];
  float acc[16];
#pragma unroll
  for (int i = 0; i < 16; i++)
    acc[i] = W0buf[((size_t)b * NN + n0 + i) * CC + t];
  for (int half = 0; half < 2; half++){
    __syncthreads();
    for (int idx = t; idx < 32 * 256; idx += 256){
      int r = idx >> 8, k = idx & 255;
      ls[r * 257 + k] = sl2[((size_t)b * SS + half * 32 + r) * CC + k];
    }
    __syncthreads();
#pragma unroll
    for (int i = 0; i < 16; i++){
      float a = acc[i];
      for (int s2 = 0; s2 < 32; s2++)
        a += lp[i * 64 + half * 32 + s2] * ls[s2 * 257 + t];
      acc[i] = a;
    }
  }
#pragma unroll
  for (int i = 0; i < 16; i++)
    W0buf[((size_t)b * NN + n0 + i) * CC + t] = acc[i];
}

// ---------------- conversion kernels ----------------
__global__ __launch_bounds__(256) void k_cvt4(const float* __restrict__ src, uint16_t* __restrict__ dst, int n4){
  int i = blockIdx.x * 256 + threadIdx.x;
  if (i >= n4) return;
  float4 v = ((const float4*)src)[i];
  u16x4 o;
  o[0] = f2b(v.x); o[1] = f2b(v.y); o[2] = f2b(v.z); o[3] = f2b(v.w);
  *(u16x4*)&dst[(size_t)i * 4] = o;
}

// build zero-padded bf16 image of channels 0..63: [B][66][66][64]
__global__ __launch_bounds__(256) void k_pad(const float* __restrict__ XN, uint16_t* __restrict__ xn2p){
  int i = blockIdx.x * 256 + threadIdx.x;  // one u16x4 (4 channels)
  int c4 = i & 15; int p = i >> 4;
  int px = p % 66; int rest = p / 66; int py = rest % 66; int b = rest / 66;
  u16x4 o; o[0] = 0; o[1] = 0; o[2] = 0; o[3] = 0;
  if (py >= 1 && py <= 64 && px >= 1 && px <= 64){
    float4 v = *(const float4*)&XN[((size_t)b * NN + (py - 1) * WW + (px - 1)) * CC + c4 * 4];
    o[0] = f2b(v.x); o[1] = f2b(v.y); o[2] = f2b(v.z); o[3] = f2b(v.w);
  }
  *(u16x4*)&xn2p[(size_t)p * 64 + c4 * 4] = o;
}

// pconv weights -> bf16 [co][tap*64+ci]
__global__ __launch_bounds__(256) void k_wp2(const float* __restrict__ pw, uint16_t* __restrict__ wp2){
  int i = blockIdx.x * 256 + threadIdx.x;
  if (i >= 64 * 576) return;
  int co = i / 576, r = i % 576, tap = r >> 6, ci = r & 63;
  wp2[i] = f2b(pw[(size_t)co * 576 + ci * 9 + tap]);
}

// ---------------- pconv as 9-tap MFMA GEMM: [65536 x 64] = im2col(xn2p) @ wp2^T ----------------
__global__ __launch_bounds__(256) void k_pconv_mfma(const uint16_t* __restrict__ xn2p,
                                                    const uint16_t* __restrict__ wp2,
                                                    uint16_t* __restrict__ pcb){
  __shared__ uint16_t lA[256 * 64];
  __shared__ uint16_t lB[64 * 64];
  int t = threadIdx.x, lane = t & 63, w = t >> 6;
  int wrow = w * 64;                 // 4 waves tile M; all waves cover full N=64
  int BR = blockIdx.x * 256;
  f32x4 acc[4][4];
#pragma unroll
  for (int m = 0; m < 4; m++)
#pragma unroll
    for (int n = 0; n < 4; n++) acc[m][n] = (f32x4){0.f, 0.f, 0.f, 0.f};
  for (int tap = 0; tap < 9; tap++){
    int dy = tap / 3 - 1, dx = tap % 3 - 1;
#pragma unroll
    for (int i = 0; i < 8; i++){     // A: 256 rows x 64k = 2048 16B-chunks
      int idx = i * 256 + t;
      int row = idx >> 3, kp = idx & 7;
      int r = BR + row;
      int b = r >> 12, n = r & 4095, y = n >> 6, x = n & 63;
      size_t p = ((size_t)(b * 66 + (y + 1 + dy)) * 66 + (x + 1 + dx)) * 64 + kp * 8;
      *(u16x8*)&lA[row * 64 + kp * 8] = *(const u16x8*)&xn2p[p];
    }
#pragma unroll
    for (int i = 0; i < 2; i++){     // B: 64 rows x 64k = 512 chunks
      int idx = i * 256 + t;
      int row = idx >> 3, kp = idx & 7;
      *(u16x8*)&lB[row * 64 + kp * 8] = *(const u16x8*)&wp2[(size_t)row * 576 + tap * 64 + kp * 8];
    }
    __syncthreads();
    mma_core(lA, lB, acc, wrow, 0, lane);
    __syncthreads();
  }
  int rb4 = (lane >> 4) * 4, cb = lane & 15;
#pragma unroll
  for (int m = 0; m < 4; m++)
#pragma unroll
    for (int n = 0; n < 4; n++)
#pragma unroll
      for (int j = 0; j < 4; j++)
        pcb[(size_t)(BR + wrow + m * 16 + rb4 + j) * 64 + (n * 16 + cb)] = f2b(acc[m][n][j]);
}

// ---------------- lin1 MFMA: [16384 x 1024] = xt @ w1^T, gelu, split to Y1b/Y2b ----------------
__global__ __launch_bounds__(256) void k_lin1_mfma(const uint16_t* __restrict__ pcb,
                                                   const uint16_t* __restrict__ xn2b,
                                                   const uint16_t* __restrict__ w1b,
                                                   const float* __restrict__ b1,
                                                   uint16_t* __restrict__ Y1b, uint16_t* __restrict__ Y2b,
                                                   int rowbase){
  __shared__ uint16_t lA[128 * 64];
  __shared__ uint16_t lB[128 * 64];
  int t = threadIdx.x, lane = t & 63, w = t >> 6;
  int wrow = (w >> 1) * 64, wcol = (w & 1) * 64;
  int BR = blockIdx.x * 128, BC = blockIdx.y * 128;
  f32x4 acc[4][4];
#pragma unroll
  for (int m = 0; m < 4; m++)
#pragma unroll
    for (int n = 0; n < 4; n++) acc[m][n] = (f32x4){0.f, 0.f, 0.f, 0.f};
  for (int kc = 0; kc < 4; kc++){
#pragma unroll
    for (int i = 0; i < 4; i++){     // A: 128 rows x 64k = 1024 chunks
      int idx = i * 256 + t;
      int row = idx >> 3, kp = idx & 7;
      size_t gr = (size_t)(rowbase + BR + row);
      const uint16_t* src = (kc == 0) ? (pcb + gr * 64 + kp * 8)
                                      : (xn2b + gr * 256 + kc * 64 + kp * 8);
      *(u16x8*)&lA[row * 64 + kp * 8] = *(const u16x8*)src;
    }
#pragma unroll
    for (int i = 0; i < 4; i++){     // B: 128 rows of w1b
      int idx = i * 256 + t;
      int row = idx >> 3, kp = idx & 7;
      *(u16x8*)&lB[row * 64 + kp * 8] = *(const u16x8*)&w1b[(size_t)(BC + row) * 256 + kc * 64 + kp * 8];
    }
    __syncthreads();
    mma_core(lA, lB, acc, wrow, wcol, lane);
    __syncthreads();
  }
  int rb4 = (lane >> 4) * 4, cb = lane & 15;
#pragma unroll
  for (int m = 0; m < 4; m++){
#pragma unroll
    for (int n = 0; n < 4; n++){
      int c = BC + wcol + n * 16 + cb;
      float bias = b1[c];
#pragma unroll
      for (int j = 0; j < 4; j++){
        size_t r = (size_t)(BR + wrow + m * 16 + rb4 + j);  // chunk-local row
        uint16_t h = f2b(geluf(acc[m][n][j] + bias));
        if (c < HID) Y1b[r * HID + c] = h;
        else         Y2b[r * HID + (c - HID)] = h;
      }
    }
  }
}

// ---------------- dwconv 3x3 depthwise + gelu, fused *Y2, bf16 ----------------
__global__ __launch_bounds__(256) void k_dwconv(const uint16_t* __restrict__ Y1b, const float* __restrict__ dww,
                                                const float* __restrict__ dwb, const uint16_t* __restrict__ Y2b,
                                                uint16_t* __restrict__ YPb){
  __shared__ float lw[HID * 9];
  __shared__ float lb[HID];
  int t = threadIdx.x;
  for (int idx = t; idx < HID * 9; idx += 256) lw[idx] = dww[idx];
  for (int idx = t; idx < HID; idx += 256) lb[idx] = dwb[idx];
  __syncthreads();
  int n = blockIdx.x; int bl = blockIdx.y;   // image within chunk
  int y = n >> 6, x = n & 63;
  const uint16_t* base = Y1b + (size_t)bl * NN * HID;
#pragma unroll
  for (int half = 0; half < 2; half++){
    int ch = half * 256 + t;
    float acc = lb[ch];
    for (int ky = 0; ky < 3; ky++){
      int iy = y + ky - 1; if (iy < 0 || iy >= HH) continue;
      for (int kx = 0; kx < 3; kx++){
        int ix = x + kx - 1; if (ix < 0 || ix >= WW) continue;
        acc += b2f(base[(size_t)(iy * WW + ix) * HID + ch]) * lw[ch * 9 + ky * 3 + kx];
      }
    }
    float y2 = b2f(Y2b[((size_t)bl * NN + n) * HID + ch]);
    YPb[((size_t)bl * NN + n) * HID + ch] = f2b(geluf(acc) * y2);
  }
}

// ---------------- lin2 MFMA: W0 += (Y1D*Y2) @ w2^T + b2 ----------------
__global__ __launch_bounds__(256) void k_lin2_mfma(const uint16_t* __restrict__ YPb,
                                                   const uint16_t* __restrict__ w2b,
                                                   const float* __restrict__ b2,
                                                   float* __restrict__ W0buf, int rowbase){
  __shared__ uint16_t lA[128 * 64];
  __shared__ uint16_t lB[128 * 64];
  int t = threadIdx.x, lane = t & 63, w = t >> 6;
  int wrow = (w >> 1) * 64, wcol = (w & 1) * 64;
  int BR = blockIdx.x * 128, BC = blockIdx.y * 128;
  f32x4 acc[4][4];
#pragma unroll
  for (int m = 0; m < 4; m++)
#pragma unroll
    for (int n = 0; n < 4; n++) acc[m][n] = (f32x4){0.f, 0.f, 0.f, 0.f};
  for (int kc = 0; kc < 8; kc++){
#pragma unroll
    for (int i = 0; i < 4; i++){
      int idx = i * 256 + t;
      int row = idx >> 3, kp = idx & 7;
      *(u16x8*)&lA[row * 64 + kp * 8] = *(const u16x8*)&YPb[(size_t)(BR + row) * HID + kc * 64 + kp * 8];
    }
#pragma unroll
    for (int i = 0; i < 4; i++){
      int idx = i * 256 + t;
      int row = idx >> 3, kp = idx & 7;
      *(u16x8*)&lB[row * 64 + kp * 8] = *(const u16x8*)&w2b[(size_t)(BC + row) * HID + kc * 64 + kp * 8];
    }
    __syncthreads();
    mma_core(lA, lB, acc, wrow, wcol, lane);
    __syncthreads();
  }
  int rb4 = (lane >> 4) * 4, cb = lane & 15;
#pragma unroll
  for (int m = 0; m < 4; m++){
#pragma unroll
    for (int n = 0; n < 4; n++){
      int c = BC + wcol + n * 16 + cb;
      float bias = b2[c];
#pragma unroll
      for (int j = 0; j < 4; j++){
        size_t gr = (size_t)(rowbase + BR + wrow + m * 16 + rb4 + j);
        W0buf[gr * CC + c] += acc[m][n][j] + bias;
      }
    }
  }
}

// ---------------- K13: final NHWC->NCHW, write both outputs ----------------
__global__ __launch_bounds__(256) void k_final(const float* __restrict__ W0buf, const float* __restrict__ xin,
                                               float* __restrict__ out){
  __shared__ float tile[32][33];
  int b = blockIdx.z;
  int n0 = blockIdx.x * 32, c0 = blockIdx.y * 32;
  int tx = threadIdx.x, ty = threadIdx.y;
  const float* src = W0buf + (size_t)b * NN * CC;
#pragma unroll
  for (int i = 0; i < 32; i += 8)
    tile[ty + i][tx] = src[(size_t)(n0 + ty + i) * CC + c0 + tx];
  __syncthreads();
  float* o1 = out + (size_t)BB * CC * NN;
#pragma unroll
  for (int i = 0; i < 32; i += 8){
    size_t gi = (size_t)b * CC * NN + (size_t)(c0 + ty + i) * NN + n0 + tx;
    float v = tile[tx][ty + i];
    out[gi] = v;
    o1[gi] = xin[gi] - v;
  }
}

extern "C" void kernel_launch(void* const* d_in, const int* in_sizes, int n_in,
                              void* d_out, int out_size, void* d_ws, size_t ws_size,
                              hipStream_t stream){
  const float* x       = (const float*)d_in[0];
  const float* scale_p = (const float*)d_in[1];
  const float* n1w     = (const float*)d_in[2];
  const float* n1b     = (const float*)d_in[3];
  const float* wi      = (const float*)d_in[4];
  const float* bi      = (const float*)d_in[5];
  const float* wo      = (const float*)d_in[6];
  const float* bo      = (const float*)d_in[7];
  const float* n2w     = (const float*)d_in[8];
  const float* n2b     = (const float*)d_in[9];
  const float* pw      = (const float*)d_in[10];
  const float* w1      = (const float*)d_in[11];
  const float* b1      = (const float*)d_in[12];
  const float* dww     = (const float*)d_in[13];
  const float* dwb     = (const float*)d_in[14];
  const float* w2      = (const float*)d_in[15];
  const float* b2      = (const float*)d_in[16];

  // ---- workspace layout (floats) ----
  float* base = (float*)d_ws;
  size_t off = 0;
  float* W0  = base + off; off += (size_t)BB * NN * CC;     // x NHWC -> x_after -> x_final
  float* SLN = base + off; off += (size_t)BB * SS * CC;
  float* SLA = base + off; off += (size_t)BB * SS * CC;
  float* QKV = base + off; off += (size_t)BB * SS * 3 * CC;
  float* AO  = base + off; off += (size_t)BB * SS * CC;
  float* SL2 = base + off; off += (size_t)BB * SS * CC;
  float* RN  = base + off; off += (size_t)BB * NN;
  float* P   = base + off; off += (size_t)BB * NN * SS;
  uint16_t* w1b = (uint16_t*)(base + off); off += (size_t)(2 * HID) * CC / 2;   // bf16, 1024x256
  uint16_t* w2b = (uint16_t*)(base + off); off += (size_t)CC * HID / 2;         // bf16, 256x512
  uint16_t* wp2 = (uint16_t*)(base + off); off += (size_t)64 * 576 / 2 + 16;    // bf16, 64x576
  if (ws_size < off * sizeof(float)) return;

  // d_out halves double as scratch until k_final rewrites everything:
  float* XN = (float*)d_out;                          // fp32 LN output (both LNs)
  float* LG = (float*)d_out + (size_t)BB * NN * CC;   // logits (attn phase)
  float* OUT = (float*)d_out;
  // FRFN phase overlays:
  uint16_t* Y1b  = (uint16_t*)d_out;                                   // [16384][512] bf16 per chunk
  uint16_t* Y2b  = Y1b + (size_t)4 * NN * HID;
  uint16_t* YPb  = Y2b + (size_t)4 * NN * HID;
  uint16_t* xn2b = (uint16_t*)LG;                                      // [65536][256] bf16
  uint16_t* xn2p = xn2b + (size_t)BB * NN * CC;                        // [16][66][66][64] bf16
  uint16_t* pcb  = xn2p + (size_t)BB * 66 * 66 * 64;                   // [65536][64] bf16

  dim3 tb2(32, 8);
  k_nchw2nhwc<<<dim3(NN / 32, CC / 32, BB), tb2, 0, stream>>>(x, W0);
  k_pool<<<BB * SS, 256, 0, stream>>>(W0, SLN);
  k_ln<<<BB * NN, 256, 0, stream>>>(W0, n1w, n1b, XN, RN);
  k_logits<<<dim3(NN / 8, SS / 32, BB), 256, 0, stream>>>(SLN, XN, RN, scale_p, LG);
  k_slots_agg<<<BB * SS, 256, 0, stream>>>(LG, XN, SLA);
  k_qkv<<<BB * SS, 256, 0, stream>>>(SLA, wi, bi, QKV);
  k_attn<<<BB * NHEAD, 256, 0, stream>>>(QKV, AO);
  k_oproj<<<BB * SS, 256, 0, stream>>>(AO, wo, bo, SL2);
  k_probsT<<<dim3(NN / 4, BB), 256, 0, stream>>>(LG, P);
  k_out_res<<<dim3(NN / 16, BB), 256, 0, stream>>>(P, SL2, W0);
  // ---- FRFN ----
  k_ln<<<BB * NN, 256, 0, stream>>>(W0, n2w, n2b, XN, (float*)nullptr);
  k_cvt4<<<(BB * NN * CC / 4) / 256, 256, 0, stream>>>(XN, xn2b, BB * NN * CC / 4);
  k_pad<<<(BB * 66 * 66 * 16) / 256, 256, 0, stream>>>(XN, xn2p);
  k_cvt4<<<(2 * HID * CC / 4 + 255) / 256, 256, 0, stream>>>(w1, w1b, 2 * HID * CC / 4);
  k_cvt4<<<(CC * HID / 4 + 255) / 256, 256, 0, stream>>>(w2, w2b, CC * HID / 4);
  k_wp2<<<(64 * 576 + 255) / 256, 256, 0, stream>>>(pw, wp2);
  k_pconv_mfma<<<BB * NN / 256, 256, 0, stream>>>(xn2p, wp2, pcb);
  for (int ch = 0; ch < 4; ch++){
    int rowbase = ch * 4 * NN;
    k_lin1_mfma<<<dim3(4 * NN / 128, 1024 / 128), 256, 0, stream>>>(pcb, xn2b, w1b, b1, Y1b, Y2b, rowbase);
    k_dwconv<<<dim3(NN, 4), 256, 0, stream>>>(Y1b, dww, dwb, Y2b, YPb);
    k_lin2_mfma<<<dim3(4 * NN / 128, CC / 128), 256, 0, stream>>>(YPb, w2b, b2, W0, rowbase);
  }
  k_final<<<dim3(NN / 32, CC / 32, BB), tb2, 0, stream>>>(W0, x, OUT);
}

// Round 3
// 791.564 us; speedup vs baseline: 3.2866x; 1.5455x over previous
//
#include <hip/hip_runtime.h>
#include <hip/hip_bf16.h>
#include <stdint.h>
#include <math.h>

#define BB 16
#define CC 256
#define HH 64
#define WW 64
#define NN 4096   // HH*WW
#define SS 64
#define NHEAD 8
#define DH 32
#define HID 512
#define DC 64

typedef float    f32x4  __attribute__((ext_vector_type(4)));
typedef uint16_t u16x8  __attribute__((ext_vector_type(8)));
typedef uint16_t u16x4  __attribute__((ext_vector_type(4)));

__device__ __forceinline__ float geluf(float x){
  return 0.5f * x * (1.0f + erff(x * 0.70710678118654752f));
}
__device__ __forceinline__ uint16_t f2b(float f){
  union { float f; uint32_t u; } v; v.f = f;
  uint32_t r = v.u + 0x7fffu + ((v.u >> 16) & 1u);
  return (uint16_t)(r >> 16);
}
__device__ __forceinline__ float b2f(uint16_t h){
  union { uint32_t u; float f; } v; v.u = ((uint32_t)h) << 16;
  return v.f;
}

__device__ __forceinline__ float waveSum(float v){
#pragma unroll
  for (int m = 32; m >= 1; m >>= 1) v += __shfl_xor(v, m, 64);
  return v;
}
__device__ __forceinline__ float blockSum256(float v, float* s4){
  v = waveSum(v);
  __syncthreads();
  if ((threadIdx.x & 63) == 0) s4[threadIdx.x >> 6] = v;
  __syncthreads();
  return s4[0] + s4[1] + s4[2] + s4[3];
}

// ---- MFMA 16x16x32 bf16 via inline asm (D=C in-place) ----
// A/B frag: lane l holds row/col (l&15), k = (l>>4)*8 + e
// D: col = lane&15, row = (lane>>4)*4 + reg   [m89-verified]
__device__ __forceinline__ void mfma_bf16(f32x4& d, u16x8 a, u16x8 b){
  asm volatile("v_mfma_f32_16x16x32_bf16 %0, %1, %2, %0" : "+v"(d) : "v"(a), "v"(b));
}

// 4x4-fragment core over one BK=64 LDS tile; lda/ldb in elements (16B-aligned)
__device__ __forceinline__ void mma_core(const uint16_t* lA, int lda, const uint16_t* lB, int ldb,
                                         f32x4 (&acc)[4][4], int wrow, int wcol, int lane){
  const int rb = lane & 15, kb = (lane >> 4) * 8;
#pragma unroll
  for (int ks = 0; ks < 2; ks++){
    u16x8 af[4], bf[4];
#pragma unroll
    for (int m = 0; m < 4; m++)
      af[m] = *(const u16x8*)&lA[(wrow + m * 16 + rb) * lda + ks * 32 + kb];
#pragma unroll
    for (int n = 0; n < 4; n++)
      bf[n] = *(const u16x8*)&lB[(wcol + n * 16 + rb) * ldb + ks * 32 + kb];
#pragma unroll
    for (int m = 0; m < 4; m++)
#pragma unroll
      for (int n = 0; n < 4; n++)
        mfma_bf16(acc[m][n], af[m], bf[n]);
  }
}

// ---------------- K0: x NCHW -> NHWC ----------------
__global__ __launch_bounds__(256) void k_nchw2nhwc(const float* __restrict__ in, float* __restrict__ out){
  __shared__ float tile[32][33];
  int b = blockIdx.z;
  int n0 = blockIdx.x * 32;
  int c0 = blockIdx.y * 32;
  int tx = threadIdx.x, ty = threadIdx.y;
  const float* src = in + (size_t)b * CC * NN;
  float* dst = out + (size_t)b * NN * CC;
#pragma unroll
  for (int i = 0; i < 32; i += 8)
    tile[ty + i][tx] = src[(size_t)(c0 + ty + i) * NN + n0 + tx];
  __syncthreads();
#pragma unroll
  for (int i = 0; i < 32; i += 8)
    dst[(size_t)(n0 + ty + i) * CC + c0 + tx] = tile[tx][ty + i];
}

// ---------------- K1: 8x8 pooled slots + l2norm -> bf16 ----------------
__global__ __launch_bounds__(256) void k_pool(const float* __restrict__ xnhwc, uint16_t* __restrict__ slotsNb){
  int bs = blockIdx.x; int b = bs >> 6, s = bs & 63;
  int sy = (s >> 3) * 8, sx = (s & 7) * 8;
  int c = threadIdx.x;
  const float* base = xnhwc + (size_t)b * NN * CC;
  float acc = 0.f;
#pragma unroll
  for (int i = 0; i < 8; i++){
    int rowbase = (sy + i) * WW + sx;
#pragma unroll
    for (int j = 0; j < 8; j++) acc += base[(size_t)(rowbase + j) * CC + c];
  }
  acc *= (1.0f / 64.0f);
  __shared__ float s4[4];
  float ss = blockSum256(acc * acc, s4);
  float inv = 1.0f / fmaxf(sqrtf(ss), 1e-12f);
  slotsNb[(size_t)bs * CC + c] = f2b(acc * inv);
}

// ---------------- wave-per-row LayerNorm -> bf16 (+ optional inv l2-norm) ----------------
__global__ __launch_bounds__(256) void k_ln_w(const float* __restrict__ xin, const float* __restrict__ w,
                                              const float* __restrict__ b, uint16_t* __restrict__ xoutb,
                                              float* __restrict__ rn){
  int row = blockIdx.x * 4 + (threadIdx.x >> 6);
  int lane = threadIdx.x & 63;
  float4 v = *(const float4*)&xin[(size_t)row * CC + lane * 4];
  float mu = waveSum(v.x + v.y + v.z + v.w) * (1.0f / CC);
  float d0 = v.x - mu, d1 = v.y - mu, d2 = v.z - mu, d3 = v.w - mu;
  float var = waveSum(d0 * d0 + d1 * d1 + d2 * d2 + d3 * d3) * (1.0f / CC);
  float inv = rsqrtf(var + 1e-5f);
  float4 wv = *(const float4*)&w[lane * 4];
  float4 bv = *(const float4*)&b[lane * 4];
  float x0 = d0 * inv * wv.x + bv.x;
  float x1 = d1 * inv * wv.y + bv.y;
  float x2 = d2 * inv * wv.z + bv.z;
  float x3 = d3 * inv * wv.w + bv.w;
  u16x4 o; o[0] = f2b(x0); o[1] = f2b(x1); o[2] = f2b(x2); o[3] = f2b(x3);
  *(u16x4*)&xoutb[(size_t)row * CC + lane * 4] = o;
  if (rn){
    float ss = waveSum(x0 * x0 + x1 * x1 + x2 * x2 + x3 * x3);
    if (lane == 0) rn[row] = 1.0f / fmaxf(sqrtf(ss), 1e-12f);
  }
}

// ---------------- logits GEMM + exp epilogue -> E bf16 [b][s][n] ----------------
// E = exp(scale * rn[n] * dot(slotsN_l2[s], xn[n]))  (|logit|<=1/16: no max needed)
__global__ __launch_bounds__(256) void k_logits_mfma(const uint16_t* __restrict__ slotsNb,
                                                     const uint16_t* __restrict__ xnb,
                                                     const float* __restrict__ rn,
                                                     const float* __restrict__ scale_p,
                                                     uint16_t* __restrict__ E){
  __shared__ uint16_t smem[20480];      // lA 64x64 | lB 256x64 ; reused as eT 64x264
  __shared__ float rnS[256];
  uint16_t* lA = smem;
  uint16_t* lB = smem + 64 * 64;
  int t = threadIdx.x, lane = t & 63, w = t >> 6;
  int b = blockIdx.y, n0 = blockIdx.x * 256;
  rnS[t] = rn[b * NN + n0 + t];
  f32x4 acc[4][4];
#pragma unroll
  for (int m = 0; m < 4; m++)
#pragma unroll
    for (int n = 0; n < 4; n++) acc[m][n] = (f32x4){0.f, 0.f, 0.f, 0.f};
  for (int kc = 0; kc < 4; kc++){
#pragma unroll
    for (int i = 0; i < 2; i++){
      int idx = i * 256 + t, row = idx >> 3, kp = idx & 7;
      *(u16x8*)&lA[row * 64 + kp * 8] = *(const u16x8*)&slotsNb[(size_t)(b * 64 + row) * 256 + kc * 64 + kp * 8];
    }
#pragma unroll
    for (int i = 0; i < 8; i++){
      int idx = i * 256 + t, row = idx >> 3, kp = idx & 7;
      *(u16x8*)&lB[row * 64 + kp * 8] = *(const u16x8*)&xnb[((size_t)b * NN + n0 + row) * 256 + kc * 64 + kp * 8];
    }
    __syncthreads();
    mma_core(lA, 64, lB, 64, acc, 0, w * 64, lane);
    __syncthreads();
  }
  // epilogue: eT[s][n_local] = exp(acc*scale*rn)
  float scale = scale_p[0];
  int rb4 = (lane >> 4) * 4, cb = lane & 15;
#pragma unroll
  for (int m = 0; m < 4; m++)
#pragma unroll
    for (int n = 0; n < 4; n++)
#pragma unroll
      for (int j = 0; j < 4; j++){
        int s = m * 16 + rb4 + j, nl = w * 64 + n * 16 + cb;
        smem[s * 264 + nl] = f2b(expf(acc[m][n][j] * scale * rnS[nl]));
      }
  __syncthreads();
#pragma unroll
  for (int i = 0; i < 8; i++){
    int idx = i * 256 + t, row = idx >> 5, cseg = idx & 31;
    *(u16x8*)&E[((size_t)b * 64 + row) * NN + n0 + cseg * 8] = *(const u16x8*)&smem[row * 264 + cseg * 8];
  }
}

// ---------------- z1: invz1[b,s] = 1 / sum_n E ----------------
__global__ __launch_bounds__(256) void k_z1(const uint16_t* __restrict__ E, float* __restrict__ invz1){
  int bs = blockIdx.x, t = threadIdx.x;
  const uint16_t* row = E + (size_t)bs * NN + t * 16;
  float s = 0.f;
#pragma unroll
  for (int i = 0; i < 16; i++) s += b2f(row[i]);
  __shared__ float s4[4];
  float z = blockSum256(s, s4);
  if (t == 0) invz1[bs] = 1.0f / z;
}

// ---------------- slots GEMM (K-split partials): part[b][ks][s][c] = E-chunk @ xn-chunk ----------------
__global__ __launch_bounds__(256) void k_slots_mfma(const uint16_t* __restrict__ E,
                                                    const uint16_t* __restrict__ xnb,
                                                    float* __restrict__ part){
  __shared__ uint16_t lA[64 * 64];
  __shared__ uint16_t lB[256 * 72];
  int t = threadIdx.x, lane = t & 63, w = t >> 6;
  int ks = blockIdx.x, b = blockIdx.y;
  f32x4 acc[4][4];
#pragma unroll
  for (int m = 0; m < 4; m++)
#pragma unroll
    for (int n = 0; n < 4; n++) acc[m][n] = (f32x4){0.f, 0.f, 0.f, 0.f};
  for (int kc = 0; kc < 4; kc++){
    int n0 = ks * 256 + kc * 64;
#pragma unroll
    for (int i = 0; i < 2; i++){
      int idx = i * 256 + t, row = idx >> 3, kp = idx & 7;
      *(u16x8*)&lA[row * 64 + kp * 8] = *(const u16x8*)&E[((size_t)b * 64 + row) * NN + n0 + kp * 8];
    }
#pragma unroll
    for (int i = 0; i < 8; i++){
      int idx = i * 256 + t, nrow = idx >> 5, cseg = idx & 31;
      u16x8 v = *(const u16x8*)&xnb[((size_t)b * NN + n0 + nrow) * 256 + cseg * 8];
#pragma unroll
      for (int j = 0; j < 8; j++) lB[(cseg * 8 + j) * 72 + nrow] = v[j];
    }
    __syncthreads();
    mma_core(lA, 64, lB, 72, acc, 0, w * 64, lane);
    __syncthreads();
  }
  int rb4 = (lane >> 4) * 4, cb = lane & 15;
#pragma unroll
  for (int m = 0; m < 4; m++)
#pragma unroll
    for (int n = 0; n < 4; n++)
#pragma unroll
      for (int j = 0; j < 4; j++){
        int s = m * 16 + rb4 + j, c = w * 64 + n * 16 + cb;
        part[(((size_t)b * 16 + ks) * 64 + s) * 256 + c] = acc[m][n][j];
      }
}

// ---------------- PT[b][n][s] = E[s][n] / sum_s E (bf16) ----------------
__global__ __launch_bounds__(256) void k_pt(const uint16_t* __restrict__ E, uint16_t* __restrict__ PT){
  __shared__ uint16_t lt[64 * 72];
  __shared__ float zs[4][64];
  int t = threadIdx.x;
  int n0 = blockIdx.x * 64, b = blockIdx.y;
#pragma unroll
  for (int i = 0; i < 2; i++){
    int idx = i * 256 + t, row = idx >> 3, kp = idx & 7;
    *(u16x8*)&lt[row * 72 + kp * 8] = *(const u16x8*)&E[((size_t)b * 64 + row) * NN + n0 + kp * 8];
  }
  __syncthreads();
  {
    int n = t & 63, g = t >> 6;
    float s = 0.f;
#pragma unroll
    for (int i = 0; i < 16; i++) s += b2f(lt[(g * 16 + i) * 72 + n]);
    zs[g][n] = s;
  }
  __syncthreads();
#pragma unroll
  for (int i = 0; i < 2; i++){
    int idx = i * 256 + t, n = idx >> 3, kp = idx & 7;
    float inv = 1.0f / (zs[0][n] + zs[1][n] + zs[2][n] + zs[3][n]);
    u16x8 o;
#pragma unroll
    for (int j = 0; j < 8; j++) o[j] = f2b(b2f(lt[(kp * 8 + j) * 72 + n]) * inv);
    *(u16x8*)&PT[((size_t)b * NN + n0 + n) * 64 + kp * 8] = o;
  }
}

// ---------------- mix GEMM: W0[n][c] += PT[n][s] @ sl2T[c][s] ----------------
__global__ __launch_bounds__(256) void k_mix(const uint16_t* __restrict__ PT, const uint16_t* __restrict__ sl2Tb,
                                             float* __restrict__ W0buf){
  __shared__ uint16_t lA[128 * 64];
  __shared__ uint16_t lB[128 * 64];
  int t = threadIdx.x, lane = t & 63, w = t >> 6;
  int wrow = (w >> 1) * 64, wcol = (w & 1) * 64;
  int BR = blockIdx.x * 128, BC = blockIdx.y * 128, b = blockIdx.z;
  f32x4 acc[4][4];
#pragma unroll
  for (int m = 0; m < 4; m++)
#pragma unroll
    for (int n = 0; n < 4; n++) acc[m][n] = (f32x4){0.f, 0.f, 0.f, 0.f};
#pragma unroll
  for (int i = 0; i < 4; i++){
    int idx = i * 256 + t, row = idx >> 3, kp = idx & 7;
    *(u16x8*)&lA[row * 64 + kp * 8] = *(const u16x8*)&PT[((size_t)b * NN + BR + row) * 64 + kp * 8];
    *(u16x8*)&lB[row * 64 + kp * 8] = *(const u16x8*)&sl2Tb[((size_t)b * 256 + BC + row) * 64 + kp * 8];
  }
  __syncthreads();
  mma_core(lA, 64, lB, 64, acc, wrow, wcol, lane);
  int rb4 = (lane >> 4) * 4, cb = lane & 15;
#pragma unroll
  for (int m = 0; m < 4; m++)
#pragma unroll
    for (int n = 0; n < 4; n++)
#pragma unroll
      for (int j = 0; j < 4; j++){
        size_t gi = ((size_t)b * NN + BR + wrow + m * 16 + rb4 + j) * 256 + BC + wcol + n * 16 + cb;
        W0buf[gi] += acc[m][n][j];
      }
}

// ---------------- qkv = (sum_p part / z1) @ Wi^T + bi ----------------
__global__ __launch_bounds__(256) void k_qkv(const float* __restrict__ part, const float* __restrict__ invz1,
                                             const float* __restrict__ wi, const float* __restrict__ bi,
                                             float* __restrict__ qkv){
  int bs = blockIdx.x; int b = bs >> 6, s = bs & 63;
  int t = threadIdx.x;
  __shared__ float srow[256];
  float a = 0.f;
#pragma unroll
  for (int p = 0; p < 16; p++)
    a += part[(((size_t)b * 16 + p) * 64 + s) * 256 + t];
  srow[t] = a * invz1[bs];
  __syncthreads();
  for (int r = 0; r < 3; r++){
    int j = r * 256 + t;
    const float* wrow = wi + (size_t)j * CC;
    float acc = bi[j];
    for (int k = 0; k < CC; k++) acc += srow[k] * wrow[k];
    qkv[(size_t)bs * 768 + j] = acc;
  }
}

// ---------------- per (b,h) attention over S=64 ----------------
__global__ __launch_bounds__(256) void k_attn(const float* __restrict__ qkv, float* __restrict__ ao){
  int b = blockIdx.x >> 3, h = blockIdx.x & 7;
  __shared__ float lq[64][33], lk[64][33], lv[64][33];
  __shared__ float sc[64][65];
  int t = threadIdx.x;
  for (int idx = t; idx < 64 * 32; idx += 256){
    int s = idx >> 5, d = idx & 31;
    const float* base = qkv + ((size_t)b * SS + s) * 768 + h * DH + d;
    lq[s][d] = base[0];
    lk[s][d] = base[256];
    lv[s][d] = base[512];
  }
  __syncthreads();
  const float rs = 0.17677669529663687f;
  for (int idx = t; idx < 64 * 64; idx += 256){
    int qq = idx >> 6, kk = idx & 63;
    float a = 0.f;
#pragma unroll
    for (int d = 0; d < 32; d++) a += lq[qq][d] * lk[kk][d];
    sc[qq][kk] = a * rs;
  }
  __syncthreads();
  if (t < 64){
    float m = -1e30f;
    for (int k = 0; k < 64; k++) m = fmaxf(m, sc[t][k]);
    float z = 0.f;
    for (int k = 0; k < 64; k++){ float e = expf(sc[t][k] - m); sc[t][k] = e; z += e; }
    float iv = 1.0f / z;
    for (int k = 0; k < 64; k++) sc[t][k] *= iv;
  }
  __syncthreads();
  for (int idx = t; idx < 64 * 32; idx += 256){
    int qq = idx >> 5, d = idx & 31;
    float a = 0.f;
#pragma unroll
    for (int k = 0; k < 64; k++) a += sc[qq][k] * lv[k][d];
    ao[((size_t)b * SS + qq) * CC + h * DH + d] = a;
  }
}

// ---------------- out projection -> sl2T bf16 [b][c][s] ----------------
__global__ __launch_bounds__(256) void k_oproj(const float* __restrict__ ao, const float* __restrict__ wo,
                                               const float* __restrict__ bo, uint16_t* __restrict__ sl2Tb){
  int bs = blockIdx.x; int b = bs >> 6, s = bs & 63;
  int t = threadIdx.x;
  __shared__ float srow[256];
  srow[t] = ao[(size_t)bs * CC + t];
  __syncthreads();
  const float* wrow = wo + (size_t)t * CC;
  float a = bo[t];
  for (int k = 0; k < CC; k++) a += srow[k] * wrow[k];
  sl2Tb[((size_t)b * 256 + t) * 64 + s] = f2b(a);
}

// ---------------- conversion kernels ----------------
__global__ __launch_bounds__(256) void k_cvt4(const float* __restrict__ src, uint16_t* __restrict__ dst, int n4){
  int i = blockIdx.x * 256 + threadIdx.x;
  if (i >= n4) return;
  float4 v = ((const float4*)src)[i];
  u16x4 o;
  o[0] = f2b(v.x); o[1] = f2b(v.y); o[2] = f2b(v.z); o[3] = f2b(v.w);
  *(u16x4*)&dst[(size_t)i * 4] = o;
}

// zero-padded bf16 image of channels 0..63: [B][66][66][64] (from bf16 NHWC)
__global__ __launch_bounds__(256) void k_pad(const uint16_t* __restrict__ xn2b, uint16_t* __restrict__ xn2p){
  int i = blockIdx.x * 256 + threadIdx.x;
  int c4 = i & 15; int p = i >> 4;
  int px = p % 66; int rest = p / 66; int py = rest % 66; int b = rest / 66;
  u16x4 o; o[0] = 0; o[1] = 0; o[2] = 0; o[3] = 0;
  if (py >= 1 && py <= 64 && px >= 1 && px <= 64)
    o = *(const u16x4*)&xn2b[((size_t)b * NN + (py - 1) * WW + (px - 1)) * CC + c4 * 4];
  *(u16x4*)&xn2p[(size_t)p * 64 + c4 * 4] = o;
}

// pconv weights -> bf16 [co][tap*64+ci]
__global__ __launch_bounds__(256) void k_wp2(const float* __restrict__ pw, uint16_t* __restrict__ wp2){
  int i = blockIdx.x * 256 + threadIdx.x;
  if (i >= 64 * 576) return;
  int co = i / 576, r = i % 576, tap = r >> 6, ci = r & 63;
  wp2[i] = f2b(pw[(size_t)co * 576 + ci * 9 + tap]);
}

// ---------------- pconv as 9-tap MFMA GEMM ----------------
__global__ __launch_bounds__(256) void k_pconv_mfma(const uint16_t* __restrict__ xn2p,
                                                    const uint16_t* __restrict__ wp2,
                                                    uint16_t* __restrict__ pcb){
  __shared__ uint16_t lA[256 * 64];
  __shared__ uint16_t lB[64 * 64];
  int t = threadIdx.x, lane = t & 63, w = t >> 6;
  int wrow = w * 64;
  int BR = blockIdx.x * 256;
  f32x4 acc[4][4];
#pragma unroll
  for (int m = 0; m < 4; m++)
#pragma unroll
    for (int n = 0; n < 4; n++) acc[m][n] = (f32x4){0.f, 0.f, 0.f, 0.f};
  for (int tap = 0; tap < 9; tap++){
    int dy = tap / 3 - 1, dx = tap % 3 - 1;
#pragma unroll
    for (int i = 0; i < 8; i++){
      int idx = i * 256 + t;
      int row = idx >> 3, kp = idx & 7;
      int r = BR + row;
      int b = r >> 12, n = r & 4095, y = n >> 6, x = n & 63;
      size_t p = ((size_t)(b * 66 + (y + 1 + dy)) * 66 + (x + 1 + dx)) * 64 + kp * 8;
      *(u16x8*)&lA[row * 64 + kp * 8] = *(const u16x8*)&xn2p[p];
    }
#pragma unroll
    for (int i = 0; i < 2; i++){
      int idx = i * 256 + t;
      int row = idx >> 3, kp = idx & 7;
      *(u16x8*)&lB[row * 64 + kp * 8] = *(const u16x8*)&wp2[(size_t)row * 576 + tap * 64 + kp * 8];
    }
    __syncthreads();
    mma_core(lA, 64, lB, 64, acc, wrow, 0, lane);
    __syncthreads();
  }
  int rb4 = (lane >> 4) * 4, cb = lane & 15;
#pragma unroll
  for (int m = 0; m < 4; m++)
#pragma unroll
    for (int n = 0; n < 4; n++)
#pragma unroll
      for (int j = 0; j < 4; j++)
        pcb[(size_t)(BR + wrow + m * 16 + rb4 + j) * 64 + (n * 16 + cb)] = f2b(acc[m][n][j]);
}

// ---------------- lin1 MFMA + gelu -> Y1b/Y2b ----------------
__global__ __launch_bounds__(256) void k_lin1_mfma(const uint16_t* __restrict__ pcb,
                                                   const uint16_t* __restrict__ xn2b,
                                                   const uint16_t* __restrict__ w1b,
                                                   const float* __restrict__ b1,
                                                   uint16_t* __restrict__ Y1b, uint16_t* __restrict__ Y2b,
                                                   int rowbase){
  __shared__ uint16_t lA[128 * 64];
  __shared__ uint16_t lB[128 * 64];
  int t = threadIdx.x, lane = t & 63, w = t >> 6;
  int wrow = (w >> 1) * 64, wcol = (w & 1) * 64;
  int BR = blockIdx.x * 128, BC = blockIdx.y * 128;
  f32x4 acc[4][4];
#pragma unroll
  for (int m = 0; m < 4; m++)
#pragma unroll
    for (int n = 0; n < 4; n++) acc[m][n] = (f32x4){0.f, 0.f, 0.f, 0.f};
  for (int kc = 0; kc < 4; kc++){
#pragma unroll
    for (int i = 0; i < 4; i++){
      int idx = i * 256 + t;
      int row = idx >> 3, kp = idx & 7;
      size_t gr = (size_t)(rowbase + BR + row);
      const uint16_t* src = (kc == 0) ? (pcb + gr * 64 + kp * 8)
                                      : (xn2b + gr * 256 + kc * 64 + kp * 8);
      *(u16x8*)&lA[row * 64 + kp * 8] = *(const u16x8*)src;
    }
#pragma unroll
    for (int i = 0; i < 4; i++){
      int idx = i * 256 + t;
      int row = idx >> 3, kp = idx & 7;
      *(u16x8*)&lB[row * 64 + kp * 8] = *(const u16x8*)&w1b[(size_t)(BC + row) * 256 + kc * 64 + kp * 8];
    }
    __syncthreads();
    mma_core(lA, 64, lB, 64, acc, wrow, wcol, lane);
    __syncthreads();
  }
  int rb4 = (lane >> 4) * 4, cb = lane & 15;
#pragma unroll
  for (int m = 0; m < 4; m++){
#pragma unroll
    for (int n = 0; n < 4; n++){
      int c = BC + wcol + n * 16 + cb;
      float bias = b1[c];
#pragma unroll
      for (int j = 0; j < 4; j++){
        size_t r = (size_t)(BR + wrow + m * 16 + rb4 + j);
        uint16_t h = f2b(geluf(acc[m][n][j] + bias));
        if (c < HID) Y1b[r * HID + c] = h;
        else         Y2b[r * HID + (c - HID)] = h;
      }
    }
  }
}

// ---------------- dwconv 3x3 + gelu, fused *Y2 ----------------
__global__ __launch_bounds__(256) void k_dwconv(const uint16_t* __restrict__ Y1b, const float* __restrict__ dww,
                                                const float* __restrict__ dwb, const uint16_t* __restrict__ Y2b,
                                                uint16_t* __restrict__ YPb){
  __shared__ float lw[HID * 9];
  __shared__ float lb[HID];
  int t = threadIdx.x;
  for (int idx = t; idx < HID * 9; idx += 256) lw[idx] = dww[idx];
  for (int idx = t; idx < HID; idx += 256) lb[idx] = dwb[idx];
  __syncthreads();
  int n = blockIdx.x; int bl = blockIdx.y;
  int y = n >> 6, x = n & 63;
  const uint16_t* base = Y1b + (size_t)bl * NN * HID;
#pragma unroll
  for (int half = 0; half < 2; half++){
    int ch = half * 256 + t;
    float acc = lb[ch];
    for (int ky = 0; ky < 3; ky++){
      int iy = y + ky - 1; if (iy < 0 || iy >= HH) continue;
      for (int kx = 0; kx < 3; kx++){
        int ix = x + kx - 1; if (ix < 0 || ix >= WW) continue;
        acc += b2f(base[(size_t)(iy * WW + ix) * HID + ch]) * lw[ch * 9 + ky * 3 + kx];
      }
    }
    float y2 = b2f(Y2b[((size_t)bl * NN + n) * HID + ch]);
    YPb[((size_t)bl * NN + n) * HID + ch] = f2b(geluf(acc) * y2);
  }
}

// ---------------- lin2 MFMA: W0 += YP @ w2^T + b2 ----------------
__global__ __launch_bounds__(256) void k_lin2_mfma(const uint16_t* __restrict__ YPb,
                                                   const uint16_t* __restrict__ w2b,
                                                   const float* __restrict__ b2,
                                                   float* __restrict__ W0buf, int rowbase){
  __shared__ uint16_t lA[128 * 64];
  __shared__ uint16_t lB[128 * 64];
  int t = threadIdx.x, lane = t & 63, w = t >> 6;
  int wrow = (w >> 1) * 64, wcol = (w & 1) * 64;
  int BR = blockIdx.x * 128, BC = blockIdx.y * 128;
  f32x4 acc[4][4];
#pragma unroll
  for (int m = 0; m < 4; m++)
#pragma unroll
    for (int n = 0; n < 4; n++) acc[m][n] = (f32x4){0.f, 0.f, 0.f, 0.f};
  for (int kc = 0; kc < 8; kc++){
#pragma unroll
    for (int i = 0; i < 4; i++){
      int idx = i * 256 + t;
      int row = idx >> 3, kp = idx & 7;
      *(u16x8*)&lA[row * 64 + kp * 8] = *(const u16x8*)&YPb[(size_t)(BR + row) * HID + kc * 64 + kp * 8];
    }
#pragma unroll
    for (int i = 0; i < 4; i++){
      int idx = i * 256 + t;
      int row = idx >> 3, kp = idx & 7;
      *(u16x8*)&lB[row * 64 + kp * 8] = *(const u16x8*)&w2b[(size_t)(BC + row) * HID + kc * 64 + kp * 8];
    }
    __syncthreads();
    mma_core(lA, 64, lB, 64, acc, wrow, wcol, lane);
    __syncthreads();
  }
  int rb4 = (lane >> 4) * 4, cb = lane & 15;
#pragma unroll
  for (int m = 0; m < 4; m++){
#pragma unroll
    for (int n = 0; n < 4; n++){
      int c = BC + wcol + n * 16 + cb;
      float bias = b2[c];
#pragma unroll
      for (int j = 0; j < 4; j++){
        size_t gr = (size_t)(rowbase + BR + wrow + m * 16 + rb4 + j);
        W0buf[gr * CC + c] += acc[m][n][j] + bias;
      }
    }
  }
}

// ---------------- final NHWC->NCHW, both outputs ----------------
__global__ __launch_bounds__(256) void k_final(const float* __restrict__ W0buf, const float* __restrict__ xin,
                                               float* __restrict__ out){
  __shared__ float tile[32][33];
  int b = blockIdx.z;
  int n0 = blockIdx.x * 32, c0 = blockIdx.y * 32;
  int tx = threadIdx.x, ty = threadIdx.y;
  const float* src = W0buf + (size_t)b * NN * CC;
#pragma unroll
  for (int i = 0; i < 32; i += 8)
    tile[ty + i][tx] = src[(size_t)(n0 + ty + i) * CC + c0 + tx];
  __syncthreads();
  float* o1 = out + (size_t)BB * CC * NN;
#pragma unroll
  for (int i = 0; i < 32; i += 8){
    size_t gi = (size_t)b * CC * NN + (size_t)(c0 + ty + i) * NN + n0 + tx;
    float v = tile[tx][ty + i];
    out[gi] = v;
    o1[gi] = xin[gi] - v;
  }
}

extern "C" void kernel_launch(void* const* d_in, const int* in_sizes, int n_in,
                              void* d_out, int out_size, void* d_ws, size_t ws_size,
                              hipStream_t stream){
  const float* x       = (const float*)d_in[0];
  const float* scale_p = (const float*)d_in[1];
  const float* n1w     = (const float*)d_in[2];
  const float* n1b     = (const float*)d_in[3];
  const float* wi      = (const float*)d_in[4];
  const float* bi      = (const float*)d_in[5];
  const float* wo      = (const float*)d_in[6];
  const float* bo      = (const float*)d_in[7];
  const float* n2w     = (const float*)d_in[8];
  const float* n2b     = (const float*)d_in[9];
  const float* pw      = (const float*)d_in[10];
  const float* w1      = (const float*)d_in[11];
  const float* b1      = (const float*)d_in[12];
  const float* dww     = (const float*)d_in[13];
  const float* dwb     = (const float*)d_in[14];
  const float* w2      = (const float*)d_in[15];
  const float* b2      = (const float*)d_in[16];

  // ---- workspace layout (float units) ----
  float* base = (float*)d_ws;
  size_t off = 0;
  float* W0   = base + off; off += (size_t)BB * NN * CC;          // x NHWC -> +mix -> +frfn
  float* part = base + off; off += (size_t)BB * 16 * SS * CC;     // slots K-split partials
  float* QKV  = base + off; off += (size_t)BB * SS * 3 * CC;
  float* AO   = base + off; off += (size_t)BB * SS * CC;
  float* RN   = base + off; off += (size_t)BB * NN;
  float* IZ1  = base + off; off += (size_t)BB * SS;
  uint16_t* slotsNb = (uint16_t*)(base + off); off += (size_t)BB * SS * CC / 2;
  uint16_t* sl2Tb   = (uint16_t*)(base + off); off += (size_t)BB * CC * SS / 2;
  uint16_t* xnb     = (uint16_t*)(base + off); off += (size_t)BB * NN * CC / 2;
  uint16_t* E       = (uint16_t*)(base + off); off += (size_t)BB * SS * NN / 2;
  uint16_t* PT      = (uint16_t*)(base + off); off += (size_t)BB * NN * SS / 2;
  uint16_t* w1b     = (uint16_t*)(base + off); off += (size_t)(2 * HID) * CC / 2;
  uint16_t* w2b     = (uint16_t*)(base + off); off += (size_t)CC * HID / 2;
  uint16_t* wp2     = (uint16_t*)(base + off); off += (size_t)64 * 576 / 2 + 16;
  if (ws_size < off * sizeof(float)) return;

  // d_out overlays (FRFN phase only; k_final rewrites all of d_out):
  uint16_t* Y1b  = (uint16_t*)d_out;
  uint16_t* Y2b  = Y1b + (size_t)4 * NN * HID;
  uint16_t* YPb  = Y2b + (size_t)4 * NN * HID;
  uint16_t* xn2b = (uint16_t*)((float*)d_out + (size_t)BB * NN * CC);
  uint16_t* xn2p = xn2b + (size_t)BB * NN * CC;
  uint16_t* pcb  = xn2p + (size_t)BB * 66 * 66 * 64;
  float* OUT = (float*)d_out;

  dim3 tb2(32, 8);
  // ---- slot-mixing phase ----
  k_nchw2nhwc<<<dim3(NN / 32, CC / 32, BB), tb2, 0, stream>>>(x, W0);
  k_pool<<<BB * SS, 256, 0, stream>>>(W0, slotsNb);
  k_ln_w<<<BB * NN / 4, 256, 0, stream>>>(W0, n1w, n1b, xnb, RN);
  k_logits_mfma<<<dim3(NN / 256, BB), 256, 0, stream>>>(slotsNb, xnb, RN, scale_p, E);
  k_z1<<<BB * SS, 256, 0, stream>>>(E, IZ1);
  k_slots_mfma<<<dim3(16, BB), 256, 0, stream>>>(E, xnb, part);
  k_qkv<<<BB * SS, 256, 0, stream>>>(part, IZ1, wi, bi, QKV);
  k_attn<<<BB * NHEAD, 256, 0, stream>>>(QKV, AO);
  k_oproj<<<BB * SS, 256, 0, stream>>>(AO, wo, bo, sl2Tb);
  k_pt<<<dim3(NN / 64, BB), 256, 0, stream>>>(E, PT);
  k_mix<<<dim3(NN / 128, CC / 128, BB), 256, 0, stream>>>(PT, sl2Tb, W0);
  // ---- FRFN phase ----
  k_ln_w<<<BB * NN / 4, 256, 0, stream>>>(W0, n2w, n2b, xn2b, (float*)nullptr);
  k_pad<<<(BB * 66 * 66 * 16) / 256, 256, 0, stream>>>(xn2b, xn2p);
  k_cvt4<<<(2 * HID * CC / 4 + 255) / 256, 256, 0, stream>>>(w1, w1b, 2 * HID * CC / 4);
  k_cvt4<<<(CC * HID / 4 + 255) / 256, 256, 0, stream>>>(w2, w2b, CC * HID / 4);
  k_wp2<<<(64 * 576 + 255) / 256, 256, 0, stream>>>(pw, wp2);
  k_pconv_mfma<<<BB * NN / 256, 256, 0, stream>>>(xn2p, wp2, pcb);
  for (int ch = 0; ch < 4; ch++){
    int rowbase = ch * 4 * NN;
    k_lin1_mfma<<<dim3(4 * NN / 128, 1024 / 128), 256, 0, stream>>>(pcb, xn2b, w1b, b1, Y1b, Y2b, rowbase);
    k_dwconv<<<dim3(NN, 4), 256, 0, stream>>>(Y1b, dww, dwb, Y2b, YPb);
    k_lin2_mfma<<<dim3(4 * NN / 128, CC / 128), 256, 0, stream>>>(YPb, w2b, b2, W0, rowbase);
  }
  k_final<<<dim3(NN / 32, CC / 32, BB), tb2, 0, stream>>>(W0, x, OUT);
}

// Round 4
// 687.280 us; speedup vs baseline: 3.7853x; 1.1517x over previous
//
#include <hip/hip_runtime.h>
#include <hip/hip_bf16.h>
#include <stdint.h>
#include <math.h>

#define BB 16
#define CC 256
#define HH 64
#define WW 64
#define NN 4096   // HH*WW
#define SS 64
#define NHEAD 8
#define DH 32
#define HID 512
#define DC 64

typedef float    f32x4  __attribute__((ext_vector_type(4)));
typedef uint16_t u16x8  __attribute__((ext_vector_type(8)));
typedef uint16_t u16x4  __attribute__((ext_vector_type(4)));

__device__ __forceinline__ float geluf(float x){
  return 0.5f * x * (1.0f + erff(x * 0.70710678118654752f));
}
__device__ __forceinline__ uint16_t f2b(float f){
  union { float f; uint32_t u; } v; v.f = f;
  uint32_t r = v.u + 0x7fffu + ((v.u >> 16) & 1u);
  return (uint16_t)(r >> 16);
}
__device__ __forceinline__ float b2f(uint16_t h){
  union { uint32_t u; float f; } v; v.u = ((uint32_t)h) << 16;
  return v.f;
}

__device__ __forceinline__ float waveSum(float v){
#pragma unroll
  for (int m = 32; m >= 1; m >>= 1) v += __shfl_xor(v, m, 64);
  return v;
}
__device__ __forceinline__ float blockSum256(float v, float* s4){
  v = waveSum(v);
  __syncthreads();
  if ((threadIdx.x & 63) == 0) s4[threadIdx.x >> 6] = v;
  __syncthreads();
  return s4[0] + s4[1] + s4[2] + s4[3];
}

// ---- MFMA 16x16x32 bf16 via inline asm (D=C in-place) ----
// A/B frag: lane l holds row/col (l&15), k = (l>>4)*8 + e
// D: col = lane&15, row = (lane>>4)*4 + reg   [m89-verified]
__device__ __forceinline__ void mfma_bf16(f32x4& d, u16x8 a, u16x8 b){
  asm volatile("v_mfma_f32_16x16x32_bf16 %0, %1, %2, %0" : "+v"(d) : "v"(a), "v"(b));
}

// 4x4-fragment core over one BK=64 LDS tile; lda/ldb in elements (16B-aligned)
__device__ __forceinline__ void mma_core(const uint16_t* lA, int lda, const uint16_t* lB, int ldb,
                                         f32x4 (&acc)[4][4], int wrow, int wcol, int lane){
  const int rb = lane & 15, kb = (lane >> 4) * 8;
#pragma unroll
  for (int ks = 0; ks < 2; ks++){
    u16x8 af[4], bf[4];
#pragma unroll
    for (int m = 0; m < 4; m++)
      af[m] = *(const u16x8*)&lA[(wrow + m * 16 + rb) * lda + ks * 32 + kb];
#pragma unroll
    for (int n = 0; n < 4; n++)
      bf[n] = *(const u16x8*)&lB[(wcol + n * 16 + rb) * ldb + ks * 32 + kb];
#pragma unroll
    for (int m = 0; m < 4; m++)
#pragma unroll
      for (int n = 0; n < 4; n++)
        mfma_bf16(acc[m][n], af[m], bf[n]);
  }
}

// ---------------- K0: x NCHW -> NHWC ----------------
__global__ __launch_bounds__(256) void k_nchw2nhwc(const float* __restrict__ in, float* __restrict__ out){
  __shared__ float tile[32][33];
  int b = blockIdx.z;
  int n0 = blockIdx.x * 32;
  int c0 = blockIdx.y * 32;
  int tx = threadIdx.x, ty = threadIdx.y;
  const float* src = in + (size_t)b * CC * NN;
  float* dst = out + (size_t)b * NN * CC;
#pragma unroll
  for (int i = 0; i < 32; i += 8)
    tile[ty + i][tx] = src[(size_t)(c0 + ty + i) * NN + n0 + tx];
  __syncthreads();
#pragma unroll
  for (int i = 0; i < 32; i += 8)
    dst[(size_t)(n0 + ty + i) * CC + c0 + tx] = tile[tx][ty + i];
}

// ---------------- K1: 8x8 pooled slots + l2norm -> bf16 ----------------
__global__ __launch_bounds__(256) void k_pool(const float* __restrict__ xnhwc, uint16_t* __restrict__ slotsNb){
  int bs = blockIdx.x; int b = bs >> 6, s = bs & 63;
  int sy = (s >> 3) * 8, sx = (s & 7) * 8;
  int c = threadIdx.x;
  const float* base = xnhwc + (size_t)b * NN * CC;
  float acc = 0.f;
#pragma unroll
  for (int i = 0; i < 8; i++){
    int rowbase = (sy + i) * WW + sx;
#pragma unroll
    for (int j = 0; j < 8; j++) acc += base[(size_t)(rowbase + j) * CC + c];
  }
  acc *= (1.0f / 64.0f);
  __shared__ float s4[4];
  float ss = blockSum256(acc * acc, s4);
  float inv = 1.0f / fmaxf(sqrtf(ss), 1e-12f);
  slotsNb[(size_t)bs * CC + c] = f2b(acc * inv);
}

// ---------------- wave-per-row LayerNorm -> bf16 (+ optional inv l2-norm) ----------------
__global__ __launch_bounds__(256) void k_ln_w(const float* __restrict__ xin, const float* __restrict__ w,
                                              const float* __restrict__ b, uint16_t* __restrict__ xoutb,
                                              float* __restrict__ rn){
  int row = blockIdx.x * 4 + (threadIdx.x >> 6);
  int lane = threadIdx.x & 63;
  float4 v = *(const float4*)&xin[(size_t)row * CC + lane * 4];
  float mu = waveSum(v.x + v.y + v.z + v.w) * (1.0f / CC);
  float d0 = v.x - mu, d1 = v.y - mu, d2 = v.z - mu, d3 = v.w - mu;
  float var = waveSum(d0 * d0 + d1 * d1 + d2 * d2 + d3 * d3) * (1.0f / CC);
  float inv = rsqrtf(var + 1e-5f);
  float4 wv = *(const float4*)&w[lane * 4];
  float4 bv = *(const float4*)&b[lane * 4];
  float x0 = d0 * inv * wv.x + bv.x;
  float x1 = d1 * inv * wv.y + bv.y;
  float x2 = d2 * inv * wv.z + bv.z;
  float x3 = d3 * inv * wv.w + bv.w;
  u16x4 o; o[0] = f2b(x0); o[1] = f2b(x1); o[2] = f2b(x2); o[3] = f2b(x3);
  *(u16x4*)&xoutb[(size_t)row * CC + lane * 4] = o;
  if (rn){
    float ss = waveSum(x0 * x0 + x1 * x1 + x2 * x2 + x3 * x3);
    if (lane == 0) rn[row] = 1.0f / fmaxf(sqrtf(ss), 1e-12f);
  }
}

// ---------------- logits GEMM + exp epilogue -> E bf16 [b][s][n] ----------------
__global__ __launch_bounds__(256) void k_logits_mfma(const uint16_t* __restrict__ slotsNb,
                                                     const uint16_t* __restrict__ xnb,
                                                     const float* __restrict__ rn,
                                                     const float* __restrict__ scale_p,
                                                     uint16_t* __restrict__ E){
  __shared__ uint16_t smem[20480];      // lA 64x64 | lB 256x64 ; reused as eT 64x264
  __shared__ float rnS[256];
  uint16_t* lA = smem;
  uint16_t* lB = smem + 64 * 64;
  int t = threadIdx.x, lane = t & 63, w = t >> 6;
  int b = blockIdx.y, n0 = blockIdx.x * 256;
  rnS[t] = rn[b * NN + n0 + t];
  f32x4 acc[4][4];
#pragma unroll
  for (int m = 0; m < 4; m++)
#pragma unroll
    for (int n = 0; n < 4; n++) acc[m][n] = (f32x4){0.f, 0.f, 0.f, 0.f};
  for (int kc = 0; kc < 4; kc++){
#pragma unroll
    for (int i = 0; i < 2; i++){
      int idx = i * 256 + t, row = idx >> 3, kp = idx & 7;
      *(u16x8*)&lA[row * 64 + kp * 8] = *(const u16x8*)&slotsNb[(size_t)(b * 64 + row) * 256 + kc * 64 + kp * 8];
    }
#pragma unroll
    for (int i = 0; i < 8; i++){
      int idx = i * 256 + t, row = idx >> 3, kp = idx & 7;
      *(u16x8*)&lB[row * 64 + kp * 8] = *(const u16x8*)&xnb[((size_t)b * NN + n0 + row) * 256 + kc * 64 + kp * 8];
    }
    __syncthreads();
    mma_core(lA, 64, lB, 64, acc, 0, w * 64, lane);
    __syncthreads();
  }
  float scale = scale_p[0];
  int rb4 = (lane >> 4) * 4, cb = lane & 15;
#pragma unroll
  for (int m = 0; m < 4; m++)
#pragma unroll
    for (int n = 0; n < 4; n++)
#pragma unroll
      for (int j = 0; j < 4; j++){
        int s = m * 16 + rb4 + j, nl = w * 64 + n * 16 + cb;
        smem[s * 264 + nl] = f2b(expf(acc[m][n][j] * scale * rnS[nl]));
      }
  __syncthreads();
#pragma unroll
  for (int i = 0; i < 8; i++){
    int idx = i * 256 + t, row = idx >> 5, cseg = idx & 31;
    *(u16x8*)&E[((size_t)b * 64 + row) * NN + n0 + cseg * 8] = *(const u16x8*)&smem[row * 264 + cseg * 8];
  }
}

// ---------------- z1: invz1[b,s] = 1 / sum_n E ----------------
__global__ __launch_bounds__(256) void k_z1(const uint16_t* __restrict__ E, float* __restrict__ invz1){
  int bs = blockIdx.x, t = threadIdx.x;
  const uint16_t* row = E + (size_t)bs * NN + t * 16;
  float s = 0.f;
#pragma unroll
  for (int i = 0; i < 16; i++) s += b2f(row[i]);
  __shared__ float s4[4];
  float z = blockSum256(s, s4);
  if (t == 0) invz1[bs] = 1.0f / z;
}

// ---------------- slots GEMM (K-split partials) ----------------
__global__ __launch_bounds__(256) void k_slots_mfma(const uint16_t* __restrict__ E,
                                                    const uint16_t* __restrict__ xnb,
                                                    float* __restrict__ part){
  __shared__ uint16_t lA[64 * 64];
  __shared__ uint16_t lB[256 * 72];
  int t = threadIdx.x, lane = t & 63, w = t >> 6;
  int ks = blockIdx.x, b = blockIdx.y;
  f32x4 acc[4][4];
#pragma unroll
  for (int m = 0; m < 4; m++)
#pragma unroll
    for (int n = 0; n < 4; n++) acc[m][n] = (f32x4){0.f, 0.f, 0.f, 0.f};
  for (int kc = 0; kc < 4; kc++){
    int n0 = ks * 256 + kc * 64;
#pragma unroll
    for (int i = 0; i < 2; i++){
      int idx = i * 256 + t, row = idx >> 3, kp = idx & 7;
      *(u16x8*)&lA[row * 64 + kp * 8] = *(const u16x8*)&E[((size_t)b * 64 + row) * NN + n0 + kp * 8];
    }
#pragma unroll
    for (int i = 0; i < 8; i++){
      int idx = i * 256 + t, nrow = idx >> 5, cseg = idx & 31;
      u16x8 v = *(const u16x8*)&xnb[((size_t)b * NN + n0 + nrow) * 256 + cseg * 8];
#pragma unroll
      for (int j = 0; j < 8; j++) lB[(cseg * 8 + j) * 72 + nrow] = v[j];
    }
    __syncthreads();
    mma_core(lA, 64, lB, 72, acc, 0, w * 64, lane);
    __syncthreads();
  }
  int rb4 = (lane >> 4) * 4, cb = lane & 15;
#pragma unroll
  for (int m = 0; m < 4; m++)
#pragma unroll
    for (int n = 0; n < 4; n++)
#pragma unroll
      for (int j = 0; j < 4; j++){
        int s = m * 16 + rb4 + j, c = w * 64 + n * 16 + cb;
        part[(((size_t)b * 16 + ks) * 64 + s) * 256 + c] = acc[m][n][j];
      }
}

// ---------------- fold partials -> slots bf16 ----------------
__global__ __launch_bounds__(256) void k_fold(const float* __restrict__ part, const float* __restrict__ invz1,
                                              uint16_t* __restrict__ slotsb){
  int i = blockIdx.x * 256 + threadIdx.x;   // over 1024*64 float4 groups
  int row = i >> 6, c4 = i & 63;
  int b = row >> 6, s = row & 63;
  float4 a = {0.f, 0.f, 0.f, 0.f};
#pragma unroll
  for (int p = 0; p < 16; p++){
    float4 v = *(const float4*)&part[(((size_t)b * 16 + p) * 64 + s) * 256 + c4 * 4];
    a.x += v.x; a.y += v.y; a.z += v.z; a.w += v.w;
  }
  float iz = invz1[row];
  u16x4 o; o[0] = f2b(a.x * iz); o[1] = f2b(a.y * iz); o[2] = f2b(a.z * iz); o[3] = f2b(a.w * iz);
  *(u16x4*)&slotsb[(size_t)row * 256 + c4 * 4] = o;
}

// ---------------- qkv GEMM: [1024 x 768] = slotsb @ wib^T + bi (fp32 out) ----------------
__global__ __launch_bounds__(256) void k_gemm_qkv(const uint16_t* __restrict__ slotsb,
                                                  const uint16_t* __restrict__ wib,
                                                  const float* __restrict__ bi,
                                                  float* __restrict__ qkv){
  __shared__ uint16_t lA[128 * 64];
  __shared__ uint16_t lB[128 * 64];
  int t = threadIdx.x, lane = t & 63, w = t >> 6;
  int wrow = (w >> 1) * 64, wcol = (w & 1) * 64;
  int BR = blockIdx.x * 128, BC = blockIdx.y * 128;
  f32x4 acc[4][4];
#pragma unroll
  for (int m = 0; m < 4; m++)
#pragma unroll
    for (int n = 0; n < 4; n++) acc[m][n] = (f32x4){0.f, 0.f, 0.f, 0.f};
  for (int kc = 0; kc < 4; kc++){
#pragma unroll
    for (int i = 0; i < 4; i++){
      int idx = i * 256 + t, row = idx >> 3, kp = idx & 7;
      *(u16x8*)&lA[row * 64 + kp * 8] = *(const u16x8*)&slotsb[(size_t)(BR + row) * 256 + kc * 64 + kp * 8];
      *(u16x8*)&lB[row * 64 + kp * 8] = *(const u16x8*)&wib[(size_t)(BC + row) * 256 + kc * 64 + kp * 8];
    }
    __syncthreads();
    mma_core(lA, 64, lB, 64, acc, wrow, wcol, lane);
    __syncthreads();
  }
  int rb4 = (lane >> 4) * 4, cb = lane & 15;
#pragma unroll
  for (int m = 0; m < 4; m++)
#pragma unroll
    for (int n = 0; n < 4; n++){
      int c = BC + wcol + n * 16 + cb;
      float bias = bi[c];
#pragma unroll
      for (int j = 0; j < 4; j++)
        qkv[(size_t)(BR + wrow + m * 16 + rb4 + j) * 768 + c] = acc[m][n][j] + bias;
    }
}

// ---------------- per (b,h) attention over S=64 -> aob bf16 ----------------
__global__ __launch_bounds__(256) void k_attn(const float* __restrict__ qkv, uint16_t* __restrict__ aob){
  int b = blockIdx.x >> 3, h = blockIdx.x & 7;
  __shared__ float lq[64][33], lk[64][33], lv[64][33];
  __shared__ float sc[64][65];
  int t = threadIdx.x;
  for (int idx = t; idx < 64 * 32; idx += 256){
    int s = idx >> 5, d = idx & 31;
    const float* base = qkv + ((size_t)b * SS + s) * 768 + h * DH + d;
    lq[s][d] = base[0];
    lk[s][d] = base[256];
    lv[s][d] = base[512];
  }
  __syncthreads();
  const float rs = 0.17677669529663687f;
  for (int idx = t; idx < 64 * 64; idx += 256){
    int qq = idx >> 6, kk = idx & 63;
    float a = 0.f;
#pragma unroll
    for (int d = 0; d < 32; d++) a += lq[qq][d] * lk[kk][d];
    sc[qq][kk] = a * rs;
  }
  __syncthreads();
  {
    int r = t >> 2, sub = t & 3;
    float m = -1e30f;
#pragma unroll
    for (int k = sub * 16; k < sub * 16 + 16; k++) m = fmaxf(m, sc[r][k]);
    m = fmaxf(m, __shfl_xor(m, 1, 64));
    m = fmaxf(m, __shfl_xor(m, 2, 64));
    float z = 0.f;
#pragma unroll
    for (int k = sub * 16; k < sub * 16 + 16; k++){
      float e = expf(sc[r][k] - m); sc[r][k] = e; z += e;
    }
    z += __shfl_xor(z, 1, 64);
    z += __shfl_xor(z, 2, 64);
    float iv = 1.0f / z;
#pragma unroll
    for (int k = sub * 16; k < sub * 16 + 16; k++) sc[r][k] *= iv;
  }
  __syncthreads();
  for (int idx = t; idx < 64 * 32; idx += 256){
    int qq = idx >> 5, d = idx & 31;
    float a = 0.f;
#pragma unroll
    for (int k = 0; k < 64; k++) a += sc[qq][k] * lv[k][d];
    aob[((size_t)b * SS + qq) * CC + h * DH + d] = f2b(a);
  }
}

// ---------------- oproj GEMM: sl2T[b][c][s] = (aob @ wob^T + bo)^T bf16 ----------------
__global__ __launch_bounds__(256) void k_gemm_oproj(const uint16_t* __restrict__ aob,
                                                    const uint16_t* __restrict__ wob,
                                                    const float* __restrict__ bo,
                                                    uint16_t* __restrict__ sl2Tb){
  __shared__ uint16_t lA[128 * 64];
  __shared__ uint16_t lB[128 * 64];
  int t = threadIdx.x, lane = t & 63, w = t >> 6;
  int wrow = (w >> 1) * 64, wcol = (w & 1) * 64;
  int BR = blockIdx.x * 128, BC = blockIdx.y * 128;
  f32x4 acc[4][4];
#pragma unroll
  for (int m = 0; m < 4; m++)
#pragma unroll
    for (int n = 0; n < 4; n++) acc[m][n] = (f32x4){0.f, 0.f, 0.f, 0.f};
  for (int kc = 0; kc < 4; kc++){
#pragma unroll
    for (int i = 0; i < 4; i++){
      int idx = i * 256 + t, row = idx >> 3, kp = idx & 7;
      *(u16x8*)&lA[row * 64 + kp * 8] = *(const u16x8*)&aob[(size_t)(BR + row) * 256 + kc * 64 + kp * 8];
      *(u16x8*)&lB[row * 64 + kp * 8] = *(const u16x8*)&wob[(size_t)(BC + row) * 256 + kc * 64 + kp * 8];
    }
    __syncthreads();
    mma_core(lA, 64, lB, 64, acc, wrow, wcol, lane);
    __syncthreads();
  }
  int rb4 = (lane >> 4) * 4, cb = lane & 15;
#pragma unroll
  for (int m = 0; m < 4; m++)
#pragma unroll
    for (int n = 0; n < 4; n++){
      int c = BC + wcol + n * 16 + cb;
      float bias = bo[c];
#pragma unroll
      for (int j = 0; j < 4; j++){
        int r = BR + wrow + m * 16 + rb4 + j;
        int b = r >> 6, s = r & 63;
        sl2Tb[((size_t)b * 256 + c) * 64 + s] = f2b(acc[m][n][j] + bias);
      }
    }
}

// ---------------- PT[b][n][s] = E[s][n] / sum_s E (bf16) ----------------
__global__ __launch_bounds__(256) void k_pt(const uint16_t* __restrict__ E, uint16_t* __restrict__ PT){
  __shared__ uint16_t lt[64 * 72];
  __shared__ float zs[4][64];
  int t = threadIdx.x;
  int n0 = blockIdx.x * 64, b = blockIdx.y;
#pragma unroll
  for (int i = 0; i < 2; i++){
    int idx = i * 256 + t, row = idx >> 3, kp = idx & 7;
    *(u16x8*)&lt[row * 72 + kp * 8] = *(const u16x8*)&E[((size_t)b * 64 + row) * NN + n0 + kp * 8];
  }
  __syncthreads();
  {
    int n = t & 63, g = t >> 6;
    float s = 0.f;
#pragma unroll
    for (int i = 0; i < 16; i++) s += b2f(lt[(g * 16 + i) * 72 + n]);
    zs[g][n] = s;
  }
  __syncthreads();
#pragma unroll
  for (int i = 0; i < 2; i++){
    int idx = i * 256 + t, n = idx >> 3, kp = idx & 7;
    float inv = 1.0f / (zs[0][n] + zs[1][n] + zs[2][n] + zs[3][n]);
    u16x8 o;
#pragma unroll
    for (int j = 0; j < 8; j++) o[j] = f2b(b2f(lt[(kp * 8 + j) * 72 + n]) * inv);
    *(u16x8*)&PT[((size_t)b * NN + n0 + n) * 64 + kp * 8] = o;
  }
}

// ---------------- mix GEMM: W0[n][c] += PT[n][s] @ sl2T[c][s] ----------------
__global__ __launch_bounds__(256) void k_mix(const uint16_t* __restrict__ PT, const uint16_t* __restrict__ sl2Tb,
                                             float* __restrict__ W0buf){
  __shared__ uint16_t lA[128 * 64];
  __shared__ uint16_t lB[128 * 64];
  int t = threadIdx.x, lane = t & 63, w = t >> 6;
  int wrow = (w >> 1) * 64, wcol = (w & 1) * 64;
  int BR = blockIdx.x * 128, BC = blockIdx.y * 128, b = blockIdx.z;
  f32x4 acc[4][4];
#pragma unroll
  for (int m = 0; m < 4; m++)
#pragma unroll
    for (int n = 0; n < 4; n++) acc[m][n] = (f32x4){0.f, 0.f, 0.f, 0.f};
#pragma unroll
  for (int i = 0; i < 4; i++){
    int idx = i * 256 + t, row = idx >> 3, kp = idx & 7;
    *(u16x8*)&lA[row * 64 + kp * 8] = *(const u16x8*)&PT[((size_t)b * NN + BR + row) * 64 + kp * 8];
    *(u16x8*)&lB[row * 64 + kp * 8] = *(const u16x8*)&sl2Tb[((size_t)b * 256 + BC + row) * 64 + kp * 8];
  }
  __syncthreads();
  mma_core(lA, 64, lB, 64, acc, wrow, wcol, lane);
  int rb4 = (lane >> 4) * 4, cb = lane & 15;
#pragma unroll
  for (int m = 0; m < 4; m++)
#pragma unroll
    for (int n = 0; n < 4; n++)
#pragma unroll
      for (int j = 0; j < 4; j++){
        size_t gi = ((size_t)b * NN + BR + wrow + m * 16 + rb4 + j) * 256 + BC + wcol + n * 16 + cb;
        W0buf[gi] += acc[m][n][j];
      }
}

// ---------------- conversion kernels ----------------
__global__ __launch_bounds__(256) void k_cvt4(const float* __restrict__ src, uint16_t* __restrict__ dst, int n4){
  int i = blockIdx.x * 256 + threadIdx.x;
  if (i >= n4) return;
  float4 v = ((const float4*)src)[i];
  u16x4 o;
  o[0] = f2b(v.x); o[1] = f2b(v.y); o[2] = f2b(v.z); o[3] = f2b(v.w);
  *(u16x4*)&dst[(size_t)i * 4] = o;
}

// zero-padded bf16 image of channels 0..63: [B][66][66][64]
__global__ __launch_bounds__(256) void k_pad(const uint16_t* __restrict__ xn2b, uint16_t* __restrict__ xn2p){
  int i = blockIdx.x * 256 + threadIdx.x;
  int c4 = i & 15; int p = i >> 4;
  int px = p % 66; int rest = p / 66; int py = rest % 66; int b = rest / 66;
  u16x4 o; o[0] = 0; o[1] = 0; o[2] = 0; o[3] = 0;
  if (py >= 1 && py <= 64 && px >= 1 && px <= 64)
    o = *(const u16x4*)&xn2b[((size_t)b * NN + (py - 1) * WW + (px - 1)) * CC + c4 * 4];
  *(u16x4*)&xn2p[(size_t)p * 64 + c4 * 4] = o;
}

// pconv weights -> bf16 [co][tap*64+ci]
__global__ __launch_bounds__(256) void k_wp2(const float* __restrict__ pw, uint16_t* __restrict__ wp2){
  int i = blockIdx.x * 256 + threadIdx.x;
  if (i >= 64 * 576) return;
  int co = i / 576, r = i % 576, tap = r >> 6, ci = r & 63;
  wp2[i] = f2b(pw[(size_t)co * 576 + ci * 9 + tap]);
}

// ---------------- pconv as 9-tap MFMA GEMM ----------------
__global__ __launch_bounds__(256) void k_pconv_mfma(const uint16_t* __restrict__ xn2p,
                                                    const uint16_t* __restrict__ wp2,
                                                    uint16_t* __restrict__ pcb){
  __shared__ uint16_t lA[256 * 64];
  __shared__ uint16_t lB[64 * 64];
  int t = threadIdx.x, lane = t & 63, w = t >> 6;
  int wrow = w * 64;
  int BR = blockIdx.x * 256;
  f32x4 acc[4][4];
#pragma unroll
  for (int m = 0; m < 4; m++)
#pragma unroll
    for (int n = 0; n < 4; n++) acc[m][n] = (f32x4){0.f, 0.f, 0.f, 0.f};
  for (int tap = 0; tap < 9; tap++){
    int dy = tap / 3 - 1, dx = tap % 3 - 1;
#pragma unroll
    for (int i = 0; i < 8; i++){
      int idx = i * 256 + t;
      int row = idx >> 3, kp = idx & 7;
      int r = BR + row;
      int b = r >> 12, n = r & 4095, y = n >> 6, x = n & 63;
      size_t p = ((size_t)(b * 66 + (y + 1 + dy)) * 66 + (x + 1 + dx)) * 64 + kp * 8;
      *(u16x8*)&lA[row * 64 + kp * 8] = *(const u16x8*)&xn2p[p];
    }
#pragma unroll
    for (int i = 0; i < 2; i++){
      int idx = i * 256 + t;
      int row = idx >> 3, kp = idx & 7;
      *(u16x8*)&lB[row * 64 + kp * 8] = *(const u16x8*)&wp2[(size_t)row * 576 + tap * 64 + kp * 8];
    }
    __syncthreads();
    mma_core(lA, 64, lB, 64, acc, wrow, 0, lane);
    __syncthreads();
  }
  int rb4 = (lane >> 4) * 4, cb = lane & 15;
#pragma unroll
  for (int m = 0; m < 4; m++)
#pragma unroll
    for (int n = 0; n < 4; n++)
#pragma unroll
      for (int j = 0; j < 4; j++)
        pcb[(size_t)(BR + wrow + m * 16 + rb4 + j) * 64 + (n * 16 + cb)] = f2b(acc[m][n][j]);
}

// ---------------- lin1 MFMA + gelu -> Y1b/Y2b ----------------
__global__ __launch_bounds__(256) void k_lin1_mfma(const uint16_t* __restrict__ pcb,
                                                   const uint16_t* __restrict__ xn2b,
                                                   const uint16_t* __restrict__ w1b,
                                                   const float* __restrict__ b1,
                                                   uint16_t* __restrict__ Y1b, uint16_t* __restrict__ Y2b,
                                                   int rowbase){
  __shared__ uint16_t lA[128 * 64];
  __shared__ uint16_t lB[128 * 64];
  int t = threadIdx.x, lane = t & 63, w = t >> 6;
  int wrow = (w >> 1) * 64, wcol = (w & 1) * 64;
  int BR = blockIdx.x * 128, BC = blockIdx.y * 128;
  f32x4 acc[4][4];
#pragma unroll
  for (int m = 0; m < 4; m++)
#pragma unroll
    for (int n = 0; n < 4; n++) acc[m][n] = (f32x4){0.f, 0.f, 0.f, 0.f};
  for (int kc = 0; kc < 4; kc++){
#pragma unroll
    for (int i = 0; i < 4; i++){
      int idx = i * 256 + t;
      int row = idx >> 3, kp = idx & 7;
      size_t gr = (size_t)(rowbase + BR + row);
      const uint16_t* src = (kc == 0) ? (pcb + gr * 64 + kp * 8)
                                      : (xn2b + gr * 256 + kc * 64 + kp * 8);
      *(u16x8*)&lA[row * 64 + kp * 8] = *(const u16x8*)src;
    }
#pragma unroll
    for (int i = 0; i < 4; i++){
      int idx = i * 256 + t;
      int row = idx >> 3, kp = idx & 7;
      *(u16x8*)&lB[row * 64 + kp * 8] = *(const u16x8*)&w1b[(size_t)(BC + row) * 256 + kc * 64 + kp * 8];
    }
    __syncthreads();
    mma_core(lA, 64, lB, 64, acc, wrow, wcol, lane);
    __syncthreads();
  }
  int rb4 = (lane >> 4) * 4, cb = lane & 15;
#pragma unroll
  for (int m = 0; m < 4; m++){
#pragma unroll
    for (int n = 0; n < 4; n++){
      int c = BC + wcol + n * 16 + cb;
      float bias = b1[c];
#pragma unroll
      for (int j = 0; j < 4; j++){
        size_t r = (size_t)(BR + wrow + m * 16 + rb4 + j);
        uint16_t h = f2b(geluf(acc[m][n][j] + bias));
        if (c < HID) Y1b[r * HID + c] = h;
        else         Y2b[r * HID + (c - HID)] = h;
      }
    }
  }
}

// ---------------- dwconv 3x3 + gelu, fused *Y2 ----------------
__global__ __launch_bounds__(256) void k_dwconv(const uint16_t* __restrict__ Y1b, const float* __restrict__ dww,
                                                const float* __restrict__ dwb, const uint16_t* __restrict__ Y2b,
                                                uint16_t* __restrict__ YPb){
  __shared__ float lw[HID * 9];
  __shared__ float lb[HID];
  int t = threadIdx.x;
  for (int idx = t; idx < HID * 9; idx += 256) lw[idx] = dww[idx];
  for (int idx = t; idx < HID; idx += 256) lb[idx] = dwb[idx];
  __syncthreads();
  int n = blockIdx.x; int bl = blockIdx.y;
  int y = n >> 6, x = n & 63;
  const uint16_t* base = Y1b + (size_t)bl * NN * HID;
#pragma unroll
  for (int half = 0; half < 2; half++){
    int ch = half * 256 + t;
    float acc = lb[ch];
    for (int ky = 0; ky < 3; ky++){
      int iy = y + ky - 1; if (iy < 0 || iy >= HH) continue;
      for (int kx = 0; kx < 3; kx++){
        int ix = x + kx - 1; if (ix < 0 || ix >= WW) continue;
        acc += b2f(base[(size_t)(iy * WW + ix) * HID + ch]) * lw[ch * 9 + ky * 3 + kx];
      }
    }
    float y2 = b2f(Y2b[((size_t)bl * NN + n) * HID + ch]);
    YPb[((size_t)bl * NN + n) * HID + ch] = f2b(geluf(acc) * y2);
  }
}

// ---------------- lin2 MFMA: W0 += YP @ w2^T + b2 ----------------
__global__ __launch_bounds__(256) void k_lin2_mfma(const uint16_t* __restrict__ YPb,
                                                   const uint16_t* __restrict__ w2b,
                                                   const float* __restrict__ b2,
                                                   float* __restrict__ W0buf, int rowbase){
  __shared__ uint16_t lA[128 * 64];
  __shared__ uint16_t lB[128 * 64];
  int t = threadIdx.x, lane = t & 63, w = t >> 6;
  int wrow = (w >> 1) * 64, wcol = (w & 1) * 64;
  int BR = blockIdx.x * 128, BC = blockIdx.y * 128;
  f32x4 acc[4][4];
#pragma unroll
  for (int m = 0; m < 4; m++)
#pragma unroll
    for (int n = 0; n < 4; n++) acc[m][n] = (f32x4){0.f, 0.f, 0.f, 0.f};
  for (int kc = 0; kc < 8; kc++){
#pragma unroll
    for (int i = 0; i < 4; i++){
      int idx = i * 256 + t;
      int row = idx >> 3, kp = idx & 7;
      *(u16x8*)&lA[row * 64 + kp * 8] = *(const u16x8*)&YPb[(size_t)(BR + row) * HID + kc * 64 + kp * 8];
    }
#pragma unroll
    for (int i = 0; i < 4; i++){
      int idx = i * 256 + t;
      int row = idx >> 3, kp = idx & 7;
      *(u16x8*)&lB[row * 64 + kp * 8] = *(const u16x8*)&w2b[(size_t)(BC + row) * HID + kc * 64 + kp * 8];
    }
    __syncthreads();
    mma_core(lA, 64, lB, 64, acc, wrow, wcol, lane);
    __syncthreads();
  }
  int rb4 = (lane >> 4) * 4, cb = lane & 15;
#pragma unroll
  for (int m = 0; m < 4; m++){
#pragma unroll
    for (int n = 0; n < 4; n++){
      int c = BC + wcol + n * 16 + cb;
      float bias = b2[c];
#pragma unroll
      for (int j = 0; j < 4; j++){
        size_t gr = (size_t)(rowbase + BR + wrow + m * 16 + rb4 + j);
        W0buf[gr * CC + c] += acc[m][n][j] + bias;
      }
    }
  }
}

// ---------------- final NHWC->NCHW, both outputs ----------------
__global__ __launch_bounds__(256) void k_final(const float* __restrict__ W0buf, const float* __restrict__ xin,
                                               float* __restrict__ out){
  __shared__ float tile[32][33];
  int b = blockIdx.z;
  int n0 = blockIdx.x * 32, c0 = blockIdx.y * 32;
  int tx = threadIdx.x, ty = threadIdx.y;
  const float* src = W0buf + (size_t)b * NN * CC;
#pragma unroll
  for (int i = 0; i < 32; i += 8)
    tile[ty + i][tx] = src[(size_t)(n0 + ty + i) * CC + c0 + tx];
  __syncthreads();
  float* o1 = out + (size_t)BB * CC * NN;
#pragma unroll
  for (int i = 0; i < 32; i += 8){
    size_t gi = (size_t)b * CC * NN + (size_t)(c0 + ty + i) * NN + n0 + tx;
    float v = tile[tx][ty + i];
    out[gi] = v;
    o1[gi] = xin[gi] - v;
  }
}

extern "C" void kernel_launch(void* const* d_in, const int* in_sizes, int n_in,
                              void* d_out, int out_size, void* d_ws, size_t ws_size,
                              hipStream_t stream){
  const float* x       = (const float*)d_in[0];
  const float* scale_p = (const float*)d_in[1];
  const float* n1w     = (const float*)d_in[2];
  const float* n1b     = (const float*)d_in[3];
  const float* wi      = (const float*)d_in[4];
  const float* bi      = (const float*)d_in[5];
  const float* wo      = (const float*)d_in[6];
  const float* bo      = (const float*)d_in[7];
  const float* n2w     = (const float*)d_in[8];
  const float* n2b     = (const float*)d_in[9];
  const float* pw      = (const float*)d_in[10];
  const float* w1      = (const float*)d_in[11];
  const float* b1      = (const float*)d_in[12];
  const float* dww     = (const float*)d_in[13];
  const float* dwb     = (const float*)d_in[14];
  const float* w2      = (const float*)d_in[15];
  const float* b2      = (const float*)d_in[16];

  // ---- workspace layout (float units) ----
  float* base = (float*)d_ws;
  size_t off = 0;
  float* W0   = base + off; off += (size_t)BB * NN * CC;
  float* part = base + off; off += (size_t)BB * 16 * SS * CC;
  float* QKV  = base + off; off += (size_t)BB * SS * 3 * CC;
  float* RN   = base + off; off += (size_t)BB * NN;
  float* IZ1  = base + off; off += (size_t)BB * SS;
  uint16_t* slotsNb = (uint16_t*)(base + off); off += (size_t)BB * SS * CC / 2;
  uint16_t* slotsb  = (uint16_t*)(base + off); off += (size_t)BB * SS * CC / 2;
  uint16_t* aob     = (uint16_t*)(base + off); off += (size_t)BB * SS * CC / 2;
  uint16_t* sl2Tb   = (uint16_t*)(base + off); off += (size_t)BB * CC * SS / 2;
  uint16_t* xnb     = (uint16_t*)(base + off); off += (size_t)BB * NN * CC / 2;
  uint16_t* E       = (uint16_t*)(base + off); off += (size_t)BB * SS * NN / 2;
  uint16_t* PT      = (uint16_t*)(base + off); off += (size_t)BB * NN * SS / 2;
  uint16_t* w1b     = (uint16_t*)(base + off); off += (size_t)(2 * HID) * CC / 2;
  uint16_t* w2b     = (uint16_t*)(base + off); off += (size_t)CC * HID / 2;
  uint16_t* wib     = (uint16_t*)(base + off); off += (size_t)(3 * CC) * CC / 2;
  uint16_t* wob     = (uint16_t*)(base + off); off += (size_t)CC * CC / 2;
  uint16_t* wp2     = (uint16_t*)(base + off); off += (size_t)64 * 576 / 2 + 16;
  if (ws_size < off * sizeof(float)) return;

  // d_out overlays (FRFN phase only; k_final rewrites all of d_out):
  uint16_t* Y1b  = (uint16_t*)d_out;
  uint16_t* Y2b  = Y1b + (size_t)4 * NN * HID;
  uint16_t* YPb  = Y2b + (size_t)4 * NN * HID;
  uint16_t* xn2b = (uint16_t*)((float*)d_out + (size_t)BB * NN * CC);
  uint16_t* xn2p = xn2b + (size_t)BB * NN * CC;
  uint16_t* pcb  = xn2p + (size_t)BB * 66 * 66 * 64;
  float* OUT = (float*)d_out;

  dim3 tb2(32, 8);
  // ---- slot-mixing phase ----
  k_nchw2nhwc<<<dim3(NN / 32, CC / 32, BB), tb2, 0, stream>>>(x, W0);
  k_pool<<<BB * SS, 256, 0, stream>>>(W0, slotsNb);
  k_ln_w<<<BB * NN / 4, 256, 0, stream>>>(W0, n1w, n1b, xnb, RN);
  k_cvt4<<<(3 * CC * CC / 4 + 255) / 256, 256, 0, stream>>>(wi, wib, 3 * CC * CC / 4);
  k_cvt4<<<(CC * CC / 4 + 255) / 256, 256, 0, stream>>>(wo, wob, CC * CC / 4);
  k_logits_mfma<<<dim3(NN / 256, BB), 256, 0, stream>>>(slotsNb, xnb, RN, scale_p, E);
  k_z1<<<BB * SS, 256, 0, stream>>>(E, IZ1);
  k_slots_mfma<<<dim3(16, BB), 256, 0, stream>>>(E, xnb, part);
  k_fold<<<(BB * SS * CC / 4) / 256, 256, 0, stream>>>(part, IZ1, slotsb);
  k_gemm_qkv<<<dim3(8, 6), 256, 0, stream>>>(slotsb, wib, bi, QKV);
  k_attn<<<BB * NHEAD, 256, 0, stream>>>(QKV, aob);
  k_gemm_oproj<<<dim3(8, 2), 256, 0, stream>>>(aob, wob, bo, sl2Tb);
  k_pt<<<dim3(NN / 64, BB), 256, 0, stream>>>(E, PT);
  k_mix<<<dim3(NN / 128, CC / 128, BB), 256, 0, stream>>>(PT, sl2Tb, W0);
  // ---- FRFN phase ----
  k_ln_w<<<BB * NN / 4, 256, 0, stream>>>(W0, n2w, n2b, xn2b, (float*)nullptr);
  k_pad<<<(BB * 66 * 66 * 16) / 256, 256, 0, stream>>>(xn2b, xn2p);
  k_cvt4<<<(2 * HID * CC / 4 + 255) / 256, 256, 0, stream>>>(w1, w1b, 2 * HID * CC / 4);
  k_cvt4<<<(CC * HID / 4 + 255) / 256, 256, 0, stream>>>(w2, w2b, CC * HID / 4);
  k_wp2<<<(64 * 576 + 255) / 256, 256, 0, stream>>>(pw, wp2);
  k_pconv_mfma<<<BB * NN / 256, 256, 0, stream>>>(xn2p, wp2, pcb);
  for (int ch = 0; ch < 4; ch++){
    int rowbase = ch * 4 * NN;
    k_lin1_mfma<<<dim3(4 * NN / 128, 1024 / 128), 256, 0, stream>>>(pcb, xn2b, w1b, b1, Y1b, Y2b, rowbase);
    k_dwconv<<<dim3(NN, 4), 256, 0, stream>>>(Y1b, dww, dwb, Y2b, YPb);
    k_lin2_mfma<<<dim3(4 * NN / 128, CC / 128), 256, 0, stream>>>(YPb, w2b, b2, W0, rowbase);
  }
  k_final<<<dim3(NN / 32, CC / 32, BB), tb2, 0, stream>>>(W0, x, OUT);
}